// Round 10
// baseline (329.393 us; speedup 1.0000x reference)
//
#include <hip/hip_runtime.h>
#include <hip/hip_cooperative_groups.h>

namespace cg = cooperative_groups;

#define D_MODEL 512
#define D4C     128   // D_MODEL / 4
#define DA_C    256
#define FACTOR_ 128
#define BS_     4096

__device__ __forceinline__ float wave_reduce_sum(float x) {
#pragma unroll
  for (int o = 32; o; o >>= 1) x += __shfl_xor(x, o, 64);
  return x;
}

// ---- ONE cooperative kernel for all sort-prep + v-vector work ----
// P0: zero cnt/cur (blocks 0..495) + vvec partials (blocks 496..511)
// P1: vvec reduce (block 0) + count histograms (all, flattened grid-stride)
// P2: exclusive scans (blocks 0..2, 256-thread version)
// P3: fill permutations (all, flattened grid-stride)
__global__ __launch_bounds__(256)
void sortprep_kernel(int* __restrict__ zbase, int n_zero,
                     const float* __restrict__ Ws01, const float* __restrict__ ws02,
                     const float* __restrict__ Ws1,  const float* __restrict__ ws2,
                     float* __restrict__ vpart, float* __restrict__ v0,
                     float* __restrict__ v1,
                     const int* __restrict__ seg1, int n1, int k1,
                     int* __restrict__ cnt1, int* __restrict__ offs1,
                     int* __restrict__ cur1, int* __restrict__ perm1,
                     const int* __restrict__ seg2, int n2, int k2,
                     int* __restrict__ cnt2, int* __restrict__ offs2,
                     int* __restrict__ cur2, int* __restrict__ perm2,
                     const int* __restrict__ seg3, int n3, int k3,
                     int* __restrict__ cnt3, int* __restrict__ offs3,
                     int* __restrict__ cur3, int* __restrict__ perm3) {
  cg::grid_group grid = cg::this_grid();
  const int bx = blockIdx.x;
  const int nb = gridDim.x;
  const int t = threadIdx.x;
  const int lane = t & 63, wid = t >> 6;

  // ---- P0 ----
  if (bx < nb - 16) {
    int i = bx * 256 + t;
    int stride = (nb - 16) * 256;
    for (; i < n_zero; i += stride) zbase[i] = 0;
  } else {
    const int r = bx - (nb - 16);     // 0..15
    const int m = r >> 3, c = r & 7;
    const float* W  = m ? Ws1 : Ws01;
    const float* w2 = m ? ws2 : ws02;
    const int a0 = c * 32;
    float s0 = 0.f, s1 = 0.f;
#pragma unroll 8
    for (int a = a0; a < a0 + 32; ++a) {
      float wa = w2[a];
      s0 += wa * W[a * D_MODEL + t];
      s1 += wa * W[a * D_MODEL + t + 256];
    }
    vpart[(m * 8 + c) * 512 + t] = s0;
    vpart[(m * 8 + c) * 512 + t + 256] = s1;
  }
  grid.sync();

  // ---- P1 ----
  if (bx == 0) {
#pragma unroll
    for (int k = 0; k < 4; ++k) {
      int idx = k * 256 + t;            // 0..1023
      int m = idx >> 9, col = idx & 511;
      float s = 0.f;
#pragma unroll
      for (int c = 0; c < 8; ++c) s += vpart[(m * 8 + c) * 512 + col];
      (m ? v1 : v0)[col] = s;
    }
  }
  {
    const int total = n1 + n2 + n3;
    int i = bx * 256 + t;
    const int stride = nb * 256;
    for (; i < total; i += stride) {
      int sg, nsg; int* cnt;
      if (i < n1)            { sg = seg1[i];            nsg = k1; cnt = cnt1; }
      else if (i < n1 + n2)  { sg = seg2[i - n1];       nsg = k2; cnt = cnt2; }
      else                   { sg = seg3[i - n1 - n2];  nsg = k3; cnt = cnt3; }
      if ((unsigned)sg < (unsigned)nsg) atomicAdd(&cnt[sg], 1);
    }
  }
  grid.sync();

  // ---- P2: scans (blocks 0..2), 256 threads ----
  if (bx < 3) {
    const int* cnt = bx == 0 ? cnt1 : (bx == 1 ? cnt2 : cnt3);
    int n = bx == 0 ? k1 : (bx == 1 ? k2 : k3);
    int* offs = bx == 0 ? offs1 : (bx == 1 ? offs2 : offs3);
    __shared__ int wsum[4];
    const int per = (n + 255) / 256;
    const int lo = min(t * per, n);
    const int hi = min(lo + per, n);
    int s = 0;
    for (int i = lo; i < hi; ++i) s += cnt[i];
    int x = s;
#pragma unroll
    for (int o = 1; o < 64; o <<= 1) {
      int y = __shfl_up(x, o, 64);
      if (lane >= o) x += y;
    }
    if (lane == 63) wsum[wid] = x;
    __syncthreads();
    if (t == 0) {
      int acc = 0;
#pragma unroll
      for (int i = 0; i < 4; ++i) { int tmp = wsum[i]; wsum[i] = acc; acc += tmp; }
      offs[n] = acc;
    }
    __syncthreads();
    int acc = wsum[wid] + (x - s);
    for (int i = lo; i < hi; ++i) { offs[i] = acc; acc += cnt[i]; }
  }
  grid.sync();

  // ---- P3: fill permutations ----
  {
    const int total = n1 + n2 + n3;
    int i = bx * 256 + t;
    const int stride = nb * 256;
    for (; i < total; i += stride) {
      int sg, nsg, row; const int* offs; int* cur; int* perm;
      if (i < n1)           { row = i;           sg = seg1[row]; nsg = k1; offs = offs1; cur = cur1; perm = perm1; }
      else if (i < n1 + n2) { row = i - n1;      sg = seg2[row]; nsg = k2; offs = offs2; cur = cur2; perm = perm2; }
      else                  { row = i - n1 - n2; sg = seg3[row]; nsg = k3; offs = offs3; cur = cur3; perm = perm3; }
      if ((unsigned)sg < (unsigned)nsg) {
        int pos = atomicAdd(&cur[sg], 1);
        perm[offs[sg] + pos] = row;
      }
    }
  }
}

// Pool one segment (wave-per-segment gather; validated r7-r9).
__device__ __forceinline__ void pool_one(const float* __restrict__ X,
                                         const int* __restrict__ perm,
                                         const int* __restrict__ offs, int g, int lane,
                                         float4 va, float4 vb, float* __restrict__ out,
                                         int orow) {
  const float4* __restrict__ X4 = (const float4*)X;
  const int s = offs[g], e = offs[g + 1];
  float4 a0 = make_float4(0.f, 0.f, 0.f, 0.f);
  float4 a1 = make_float4(0.f, 0.f, 0.f, 0.f);
  float z = 0.f;
  for (int p = s; p < e; ++p) {
    int row = perm[p];
    float4 x0 = X4[(size_t)row * D4C + lane * 2];
    float4 x1 = X4[(size_t)row * D4C + lane * 2 + 1];
    float d = x0.x * va.x + x0.y * va.y + x0.z * va.z + x0.w * va.w
            + x1.x * vb.x + x1.y * vb.y + x1.z * vb.z + x1.w * vb.w;
    d = wave_reduce_sum(d);
    float w = expf(d);
    z += w;
    a0.x += w * x0.x; a0.y += w * x0.y; a0.z += w * x0.z; a0.w += w * x0.w;
    a1.x += w * x1.x; a1.y += w * x1.y; a1.z += w * x1.z; a1.w += w * x1.w;
  }
  float inv = (z > 0.f) ? 1.0f / z : 0.f;
  a0.x *= inv; a0.y *= inv; a0.z *= inv; a0.w *= inv;
  a1.x *= inv; a1.y *= inv; a1.z *= inv; a1.w *= inv;
  float4* __restrict__ O4 = (float4*)out;
  O4[(size_t)orow * D4C + lane * 2]     = a0;
  O4[(size_t)orow * D4C + lane * 2 + 1] = a1;
}

// ---- mega pool (VALIDATED r9, unchanged) ----
__global__ __launch_bounds__(256)
void mega_pool_kernel(const float* __restrict__ pieces,
                      const int* __restrict__ perm1, const int* __restrict__ offs1,
                      const int* __restrict__ perm2, const int* __restrict__ offs2,
                      const int* __restrict__ user_seg, int n_uni,
                      const float* __restrict__ itemj_piece,
                      const int* __restrict__ permj, const int* __restrict__ offsj,
                      const float* __restrict__ v0, const float* __restrict__ v1,
                      float* __restrict__ user_rep, float* __restrict__ itemi_out,
                      float* __restrict__ itemj_out, const int* __restrict__ pos_ptr) {
  const int bx = blockIdx.x;
  const int t = threadIdx.x;
  const int wid = t >> 6, lane = t & 63;
  const float4* __restrict__ V0 = (const float4*)v0;

  if (bx < BS_) {
    const float4* __restrict__ V1 = (const float4*)v1;
    const float4* __restrict__ X4 = (const float4*)pieces;
    float4 va0 = V0[lane * 2], vb0 = V0[lane * 2 + 1];
    float4 va1 = V1[lane * 2], vb1 = V1[lane * 2 + 1];
    int pos = *pos_ptr;
    pos = min(max(pos, 0), n_uni - BS_);
    const int u = bx;
    const int s2 = offs2[u], e2 = offs2[u + 1];

    float4 acc0 = make_float4(0.f, 0.f, 0.f, 0.f);
    float4 acc1 = make_float4(0.f, 0.f, 0.f, 0.f);
    float zz = 0.f;
    for (int k = s2 + wid; k < e2; k += 4) {
      const int rr = perm2[k];
      const int s1 = offs1[rr], e1 = offs1[rr + 1];
      float4 r0 = make_float4(0.f, 0.f, 0.f, 0.f);
      float4 r1 = make_float4(0.f, 0.f, 0.f, 0.f);
      float z1 = 0.f;
      for (int p = s1; p < e1; ++p) {
        int prow = perm1[p];
        float4 x0 = X4[(size_t)prow * D4C + lane * 2];
        float4 x1 = X4[(size_t)prow * D4C + lane * 2 + 1];
        float d = x0.x * va0.x + x0.y * va0.y + x0.z * va0.z + x0.w * va0.w
                + x1.x * vb0.x + x1.y * vb0.y + x1.z * vb0.z + x1.w * vb0.w;
        d = wave_reduce_sum(d);
        float w = expf(d);
        z1 += w;
        r0.x += w * x0.x; r0.y += w * x0.y; r0.z += w * x0.z; r0.w += w * x0.w;
        r1.x += w * x1.x; r1.y += w * x1.y; r1.z += w * x1.z; r1.w += w * x1.w;
      }
      float inv1 = (z1 > 0.f) ? 1.0f / z1 : 0.f;
      r0.x *= inv1; r0.y *= inv1; r0.z *= inv1; r0.w *= inv1;
      r1.x *= inv1; r1.y *= inv1; r1.z *= inv1; r1.w *= inv1;
      if (rr >= pos && rr < pos + BS_) {
        float4* __restrict__ O2 = (float4*)itemi_out;
        O2[(size_t)(rr - pos) * D4C + lane * 2]     = r0;
        O2[(size_t)(rr - pos) * D4C + lane * 2 + 1] = r1;
      }
      float d1 = r0.x * va1.x + r0.y * va1.y + r0.z * va1.z + r0.w * va1.w
               + r1.x * vb1.x + r1.y * vb1.y + r1.z * vb1.z + r1.w * vb1.w;
      d1 = wave_reduce_sum(d1);
      float e2w = expf(d1);
      zz += e2w;
      acc0.x += e2w * r0.x; acc0.y += e2w * r0.y;
      acc0.z += e2w * r0.z; acc0.w += e2w * r0.w;
      acc1.x += e2w * r1.x; acc1.y += e2w * r1.y;
      acc1.z += e2w * r1.z; acc1.w += e2w * r1.w;
    }
    __shared__ float4 pbuf[4][130];
    __shared__ float zbuf[4];
    pbuf[wid][lane * 2]     = acc0;
    pbuf[wid][lane * 2 + 1] = acc1;
    if (lane == 0) zbuf[wid] = zz;
    __syncthreads();
    if (wid == 0) {
      float4 A0 = make_float4(0.f, 0.f, 0.f, 0.f);
      float4 A1 = make_float4(0.f, 0.f, 0.f, 0.f);
      float Z = zbuf[0] + zbuf[1] + zbuf[2] + zbuf[3];
#pragma unroll
      for (int w = 0; w < 4; ++w) {
        float4 p0 = pbuf[w][lane * 2], p1 = pbuf[w][lane * 2 + 1];
        A0.x += p0.x; A0.y += p0.y; A0.z += p0.z; A0.w += p0.w;
        A1.x += p1.x; A1.y += p1.y; A1.z += p1.z; A1.w += p1.w;
      }
      float inv = (Z > 0.f) ? 1.0f / Z : 0.f;
      A0.x *= inv; A0.y *= inv; A0.z *= inv; A0.w *= inv;
      A1.x *= inv; A1.y *= inv; A1.z *= inv; A1.w *= inv;
      float4* __restrict__ O4 = (float4*)user_rep;
      O4[(size_t)u * D4C + lane * 2]     = A0;
      O4[(size_t)u * D4C + lane * 2 + 1] = A1;
    }
    return;
  }

  const int gridB = (BS_ + 3) >> 2;
  float4 va = V0[lane * 2], vb = V0[lane * 2 + 1];
  if (bx < BS_ + gridB) {
    int g = (bx - BS_) * 4 + wid;
    if (g >= BS_) return;
    pool_one(itemj_piece, permj, offsj, g, lane, va, vb, itemj_out, g);
  } else {
    int idx = (bx - BS_ - gridB) * 4 + wid;
    if (idx >= BS_) return;
    int pos = *pos_ptr;
    pos = min(max(pos, 0), n_uni - BS_);
    int rr = pos + idx;
    if ((unsigned)user_seg[rr] < (unsigned)BS_) return;
    pool_one(pieces, perm1, offs1, rr, lane, va, vb, itemi_out, idx);
  }
}

// ---- fused latents + BPR scores (VALIDATED r8/r9, unchanged) ----
__global__ __launch_bounds__(1024)
void latpred_kernel(const float* __restrict__ user_rep, const float* __restrict__ itemi,
                    const float* __restrict__ itemj,
                    const float* __restrict__ user_W, const float* __restrict__ user_b,
                    const float* __restrict__ item_W, const float* __restrict__ item_b,
                    float* __restrict__ pred_i, float* __restrict__ pred_j) {
  const int rows0 = blockIdx.x * 8;
  const int t = threadIdx.x;

  __shared__ float4 lAu[8][129], lAi[8][129], lAj[8][129];
  __shared__ float si[8][129], sj[8][129];
  {
    const int r = t >> 7, c = t & 127;
    lAu[r][c] = ((const float4*)user_rep)[(size_t)(rows0 + r) * D4C + c];
    lAi[r][c] = ((const float4*)itemi)[(size_t)(rows0 + r) * D4C + c];
    lAj[r][c] = ((const float4*)itemj)[(size_t)(rows0 + r) * D4C + c];
  }
  __syncthreads();

  const int row = t & 7;
  const int f   = t >> 3;
  const float4* __restrict__ Wu = (const float4*)user_W;
  const float4* __restrict__ Wi = (const float4*)item_W;
  float au = 0.f, ai = 0.f, aj = 0.f;
  for (int k4 = 0; k4 < D4C; ++k4) {
    float4 u = lAu[row][k4];
    float4 i4 = lAi[row][k4];
    float4 j4 = lAj[row][k4];
    float4 wu = Wu[(size_t)f * D4C + k4];
    float4 wi = Wi[(size_t)f * D4C + k4];
    au += u.x * wu.x + u.y * wu.y + u.z * wu.z + u.w * wu.w;
    ai += i4.x * wi.x + i4.y * wi.y + i4.z * wi.z + i4.w * wi.w;
    aj += j4.x * wi.x + j4.y * wi.y + j4.z * wi.z + j4.w * wi.w;
  }
  float lu = au + user_b[f];
  float li = ai + item_b[f];
  float lj = aj + item_b[f];
  si[row][f] = lu * li;
  sj[row][f] = lu * lj;
  __syncthreads();

  const int wid = t >> 6, lane = t & 63;
  if (wid < 8) {
    float v = si[wid][lane] + si[wid][lane + 64];
    v = wave_reduce_sum(v);
    if (lane == 0) pred_i[rows0 + wid] = v;
  } else {
    int r = wid - 8;
    float v = sj[r][lane] + sj[r][lane + 64];
    v = wave_reduce_sum(v);
    if (lane == 0) pred_j[rows0 + r] = v;
  }
}

extern "C" void kernel_launch(void* const* d_in, const int* in_sizes, int n_in,
                              void* d_out, int out_size, void* d_ws, size_t ws_size,
                              hipStream_t stream) {
  const float* user_pooled = (const float*)d_in[0];
  const float* itemj_piece = (const float*)d_in[1];
  const float* Ws1   = (const float*)d_in[2];
  const float* ws2   = (const float*)d_in[3];
  const float* Ws01  = (const float*)d_in[4];
  const float* ws02  = (const float*)d_in[5];
  const float* user_W = (const float*)d_in[6];
  const float* user_b = (const float*)d_in[7];
  const float* item_W = (const float*)d_in[8];
  const float* item_b = (const float*)d_in[9];
  const int* piece_seg = (const int*)d_in[10];
  const int* user_seg  = (const int*)d_in[11];
  const int* itemj_seg = (const int*)d_in[12];
  const int* pos_ptr   = (const int*)d_in[13];

  int P_U  = in_sizes[10];
  int NUNI = in_sizes[11];
  int P_J  = in_sizes[12];

  float* ws = (float*)d_ws;
  float* v0 = ws;                                    // 512
  float* v1 = ws + 512;                              // 512
  float* vpart = ws + 1024;                          // 8192
  float* user_rep = vpart + 8192;                    // BS*512
  int* ib = (int*)(user_rep + (size_t)BS_ * D_MODEL);
  int* perm1 = ib;                 ib += P_U;
  int* perm2 = ib;                 ib += NUNI;
  int* permj = ib;                 ib += P_J;
  int* offs1 = ib;                 ib += NUNI + 1;
  int* offs2 = ib;                 ib += BS_ + 1;
  int* offsj = ib;                 ib += BS_ + 1;
  int* cnt1  = ib;                 ib += NUNI;   // cnt*/cur* contiguous: one zero
  int* cnt2  = ib;                 ib += BS_;
  int* cntj  = ib;                 ib += BS_;
  int* cur1  = ib;                 ib += NUNI;
  int* cur2  = ib;                 ib += BS_;
  int* curj  = ib;                 ib += BS_;
  int n_zero = 2 * (NUNI + BS_ + BS_);

  float* outf = (float*)d_out;
  float* itemi_out = outf;
  float* itemj_out = outf + (size_t)BS_ * D_MODEL;
  float* pred_i = outf + 2 * (size_t)BS_ * D_MODEL;
  float* pred_j = pred_i + BS_;

  // L1: ALL sort-prep in one cooperative kernel (4 phases, 3 grid syncs)
  int k1 = NUNI, k2 = BS_, k3 = BS_;
  void* args[] = {
    (void*)&cnt1, (void*)&n_zero,
    (void*)&Ws01, (void*)&ws02, (void*)&Ws1, (void*)&ws2,
    (void*)&vpart, (void*)&v0, (void*)&v1,
    (void*)&piece_seg, (void*)&P_U, (void*)&k1,
    (void*)&cnt1, (void*)&offs1, (void*)&cur1, (void*)&perm1,
    (void*)&user_seg, (void*)&NUNI, (void*)&k2,
    (void*)&cnt2, (void*)&offs2, (void*)&cur2, (void*)&perm2,
    (void*)&itemj_seg, (void*)&P_J, (void*)&k3,
    (void*)&cntj, (void*)&offsj, (void*)&curj, (void*)&permj,
  };
  hipLaunchCooperativeKernel((const void*)sortprep_kernel, dim3(512), dim3(256),
                             args, 0, stream);

  // L2: fused pools (user path + itemj + itemi-fix)
  const int gridB = (BS_ + 3) / 4, gridC = (BS_ + 3) / 4;
  mega_pool_kernel<<<BS_ + gridB + gridC, 256, 0, stream>>>(
      user_pooled, perm1, offs1, perm2, offs2, user_seg, NUNI,
      itemj_piece, permj, offsj, v0, v1,
      user_rep, itemi_out, itemj_out, pos_ptr);

  // L3: latents + scores
  latpred_kernel<<<BS_ / 8, 1024, 0, stream>>>(user_rep, itemi_out, itemj_out,
                                               user_W, user_b, item_W, item_b,
                                               pred_i, pred_j);
}

// Round 11
// 236.543 us; speedup vs baseline: 1.3925x; 1.3925x over previous
//
#include <hip/hip_runtime.h>

#define D_MODEL 512
#define D4C     128   // D_MODEL / 4
#define DA_C    256
#define FACTOR_ 128
#define BS_     4096
#define HALFK   12288  // LDS counter window (48 KB)

__device__ __forceinline__ float wave_reduce_sum(float x) {
#pragma unroll
  for (int o = 32; o; o >>= 1) x += __shfl_xor(x, o, 64);
  return x;
}

// ---- ONE ordinary launch for all prep: 3 in-block counting sorts + vvec ----
// Blocks 0..2: full counting sort of one seg array (zero/count/scan/fill),
//   entirely within the block via __syncthreads (NO grid sync — r10 lesson).
//   Counter range processed in <=12288-wide halves so LDS stays at 48 KB.
// Blocks 3..10: v = W^T w2, col-partitioned, deterministic tree reduction.
__global__ __launch_bounds__(1024)
void prep_kernel(const int* __restrict__ seg1, int n1, int k1,
                 int* __restrict__ offs1, int* __restrict__ perm1,
                 const int* __restrict__ seg2, int n2, int k2,
                 int* __restrict__ offs2, int* __restrict__ perm2,
                 const int* __restrict__ seg3, int n3, int k3,
                 int* __restrict__ offs3, int* __restrict__ perm3,
                 const float* __restrict__ Ws01, const float* __restrict__ ws02,
                 const float* __restrict__ Ws1,  const float* __restrict__ ws2,
                 float* __restrict__ v0, float* __restrict__ v1) {
  __shared__ int cntS[HALFK];     // 48 KB sort scratch
  __shared__ int wpre[17];
  __shared__ float vred[8][128];  // 4 KB vvec scratch

  const int bx = blockIdx.x;
  const int t = threadIdx.x;
  const int lane = t & 63, wid = t >> 6;

  if (bx < 3) {
    const int* seg = bx == 0 ? seg1 : (bx == 1 ? seg2 : seg3);
    const int n    = bx == 0 ? n1 : (bx == 1 ? n2 : n3);
    const int k    = bx == 0 ? k1 : (bx == 1 ? k2 : k3);
    int* offs      = bx == 0 ? offs1 : (bx == 1 ? offs2 : offs3);
    int* perm      = bx == 0 ? perm1 : (bx == 1 ? perm2 : perm3);

    int base = 0;
    for (int h0 = 0; h0 < k; h0 += HALFK) {
      const int hk = min(k - h0, HALFK);
      // zero counters
      for (int i = t; i < hk; i += 1024) cntS[i] = 0;
      __syncthreads();
      // count (VALUE-DRIVEN: uses seg content only; OOR dropped)
      for (int i = t; i < n; i += 1024) {
        int lsg = seg[i] - h0;
        if ((unsigned)lsg < (unsigned)hk) atomicAdd(&cntS[lsg], 1);
      }
      __syncthreads();
      // exclusive scan of cntS[0..hk) -> offs[h0..h0+hk), with global base
      const int per = (hk + 1023) / 1024;
      const int lo = min(t * per, hk), hi = min(lo + per, hk);
      int s = 0;
      for (int i = lo; i < hi; ++i) s += cntS[i];
      int x = s;
#pragma unroll
      for (int o = 1; o < 64; o <<= 1) {
        int y = __shfl_up(x, o, 64);
        if (lane >= o) x += y;
      }
      if (lane == 63) wpre[wid] = x;
      __syncthreads();
      if (t == 0) {
        int acc = 0;
#pragma unroll
        for (int i = 0; i < 16; ++i) { int tmp = wpre[i]; wpre[i] = acc; acc += tmp; }
        wpre[16] = acc;   // half total
      }
      __syncthreads();
      int acc = base + wpre[wid] + (x - s);
      for (int i = lo; i < hi; ++i) { offs[h0 + i] = acc; acc += cntS[i]; }
      const int halftot = wpre[16];
      __syncthreads();
      // re-zero as cur
      for (int i = t; i < hk; i += 1024) cntS[i] = 0;
      __syncthreads();
      // fill permutation (offs read back: same block wrote it, sync'd above)
      for (int i = t; i < n; i += 1024) {
        int sg = seg[i];
        int lsg = sg - h0;
        if ((unsigned)lsg < (unsigned)hk) {
          int pos = atomicAdd(&cntS[lsg], 1);
          perm[offs[sg] + pos] = i;
        }
      }
      base += halftot;
      __syncthreads();
    }
    if (t == 0) offs[k] = base;
    return;
  }

  // vvec blocks: bx-3 = vb in 0..7 ; matrix m = vb>>2, col window (vb&3)*128
  const int vb = bx - 3;
  const int m = vb >> 2;
  const int c0 = (vb & 3) * 128;
  const float* W  = m ? Ws1 : Ws01;
  const float* w2 = m ? ws2 : ws02;
  const int col_i = t & 127;
  const int g = t >> 7;            // 0..7, 32 a-rows each
  float s = 0.f;
  for (int a = g * 32; a < g * 32 + 32; ++a)
    s += w2[a] * W[a * D_MODEL + c0 + col_i];
  vred[g][col_i] = s;
  __syncthreads();
  if (t < 128) {
    float acc = 0.f;
#pragma unroll
    for (int g2 = 0; g2 < 8; ++g2) acc += vred[g2][t];
    (m ? v1 : v0)[c0 + t] = acc;
  }
}

// Pool one segment (wave-per-segment gather; VALIDATED r7-r9).
__device__ __forceinline__ void pool_one(const float* __restrict__ X,
                                         const int* __restrict__ perm,
                                         const int* __restrict__ offs, int g, int lane,
                                         float4 va, float4 vb, float* __restrict__ out,
                                         int orow) {
  const float4* __restrict__ X4 = (const float4*)X;
  const int s = offs[g], e = offs[g + 1];
  float4 a0 = make_float4(0.f, 0.f, 0.f, 0.f);
  float4 a1 = make_float4(0.f, 0.f, 0.f, 0.f);
  float z = 0.f;
  for (int p = s; p < e; ++p) {
    int row = perm[p];
    float4 x0 = X4[(size_t)row * D4C + lane * 2];
    float4 x1 = X4[(size_t)row * D4C + lane * 2 + 1];
    float d = x0.x * va.x + x0.y * va.y + x0.z * va.z + x0.w * va.w
            + x1.x * vb.x + x1.y * vb.y + x1.z * vb.z + x1.w * vb.w;
    d = wave_reduce_sum(d);
    float w = expf(d);
    z += w;
    a0.x += w * x0.x; a0.y += w * x0.y; a0.z += w * x0.z; a0.w += w * x0.w;
    a1.x += w * x1.x; a1.y += w * x1.y; a1.z += w * x1.z; a1.w += w * x1.w;
  }
  float inv = (z > 0.f) ? 1.0f / z : 0.f;
  a0.x *= inv; a0.y *= inv; a0.z *= inv; a0.w *= inv;
  a1.x *= inv; a1.y *= inv; a1.z *= inv; a1.w *= inv;
  float4* __restrict__ O4 = (float4*)out;
  O4[(size_t)orow * D4C + lane * 2]     = a0;
  O4[(size_t)orow * D4C + lane * 2 + 1] = a1;
}

// ---- mega pool (VALIDATED r9, verbatim) ----
__global__ __launch_bounds__(256)
void mega_pool_kernel(const float* __restrict__ pieces,
                      const int* __restrict__ perm1, const int* __restrict__ offs1,
                      const int* __restrict__ perm2, const int* __restrict__ offs2,
                      const int* __restrict__ user_seg, int n_uni,
                      const float* __restrict__ itemj_piece,
                      const int* __restrict__ permj, const int* __restrict__ offsj,
                      const float* __restrict__ v0, const float* __restrict__ v1,
                      float* __restrict__ user_rep, float* __restrict__ itemi_out,
                      float* __restrict__ itemj_out, const int* __restrict__ pos_ptr) {
  const int bx = blockIdx.x;
  const int t = threadIdx.x;
  const int wid = t >> 6, lane = t & 63;
  const float4* __restrict__ V0 = (const float4*)v0;

  if (bx < BS_) {
    const float4* __restrict__ V1 = (const float4*)v1;
    const float4* __restrict__ X4 = (const float4*)pieces;
    float4 va0 = V0[lane * 2], vb0 = V0[lane * 2 + 1];
    float4 va1 = V1[lane * 2], vb1 = V1[lane * 2 + 1];
    int pos = *pos_ptr;
    pos = min(max(pos, 0), n_uni - BS_);
    const int u = bx;
    const int s2 = offs2[u], e2 = offs2[u + 1];

    float4 acc0 = make_float4(0.f, 0.f, 0.f, 0.f);
    float4 acc1 = make_float4(0.f, 0.f, 0.f, 0.f);
    float zz = 0.f;
    for (int k = s2 + wid; k < e2; k += 4) {
      const int rr = perm2[k];
      const int s1 = offs1[rr], e1 = offs1[rr + 1];
      float4 r0 = make_float4(0.f, 0.f, 0.f, 0.f);
      float4 r1 = make_float4(0.f, 0.f, 0.f, 0.f);
      float z1 = 0.f;
      for (int p = s1; p < e1; ++p) {
        int prow = perm1[p];
        float4 x0 = X4[(size_t)prow * D4C + lane * 2];
        float4 x1 = X4[(size_t)prow * D4C + lane * 2 + 1];
        float d = x0.x * va0.x + x0.y * va0.y + x0.z * va0.z + x0.w * va0.w
                + x1.x * vb0.x + x1.y * vb0.y + x1.z * vb0.z + x1.w * vb0.w;
        d = wave_reduce_sum(d);
        float w = expf(d);
        z1 += w;
        r0.x += w * x0.x; r0.y += w * x0.y; r0.z += w * x0.z; r0.w += w * x0.w;
        r1.x += w * x1.x; r1.y += w * x1.y; r1.z += w * x1.z; r1.w += w * x1.w;
      }
      float inv1 = (z1 > 0.f) ? 1.0f / z1 : 0.f;
      r0.x *= inv1; r0.y *= inv1; r0.z *= inv1; r0.w *= inv1;
      r1.x *= inv1; r1.y *= inv1; r1.z *= inv1; r1.w *= inv1;
      if (rr >= pos && rr < pos + BS_) {
        float4* __restrict__ O2 = (float4*)itemi_out;
        O2[(size_t)(rr - pos) * D4C + lane * 2]     = r0;
        O2[(size_t)(rr - pos) * D4C + lane * 2 + 1] = r1;
      }
      float d1 = r0.x * va1.x + r0.y * va1.y + r0.z * va1.z + r0.w * va1.w
               + r1.x * vb1.x + r1.y * vb1.y + r1.z * vb1.z + r1.w * vb1.w;
      d1 = wave_reduce_sum(d1);
      float e2w = expf(d1);
      zz += e2w;
      acc0.x += e2w * r0.x; acc0.y += e2w * r0.y;
      acc0.z += e2w * r0.z; acc0.w += e2w * r0.w;
      acc1.x += e2w * r1.x; acc1.y += e2w * r1.y;
      acc1.z += e2w * r1.z; acc1.w += e2w * r1.w;
    }
    __shared__ float4 pbuf[4][130];
    __shared__ float zbuf[4];
    pbuf[wid][lane * 2]     = acc0;
    pbuf[wid][lane * 2 + 1] = acc1;
    if (lane == 0) zbuf[wid] = zz;
    __syncthreads();
    if (wid == 0) {
      float4 A0 = make_float4(0.f, 0.f, 0.f, 0.f);
      float4 A1 = make_float4(0.f, 0.f, 0.f, 0.f);
      float Z = zbuf[0] + zbuf[1] + zbuf[2] + zbuf[3];
#pragma unroll
      for (int w = 0; w < 4; ++w) {
        float4 p0 = pbuf[w][lane * 2], p1 = pbuf[w][lane * 2 + 1];
        A0.x += p0.x; A0.y += p0.y; A0.z += p0.z; A0.w += p0.w;
        A1.x += p1.x; A1.y += p1.y; A1.z += p1.z; A1.w += p1.w;
      }
      float inv = (Z > 0.f) ? 1.0f / Z : 0.f;
      A0.x *= inv; A0.y *= inv; A0.z *= inv; A0.w *= inv;
      A1.x *= inv; A1.y *= inv; A1.z *= inv; A1.w *= inv;
      float4* __restrict__ O4 = (float4*)user_rep;
      O4[(size_t)u * D4C + lane * 2]     = A0;
      O4[(size_t)u * D4C + lane * 2 + 1] = A1;
    }
    return;
  }

  const int gridB = (BS_ + 3) >> 2;
  float4 va = V0[lane * 2], vb = V0[lane * 2 + 1];
  if (bx < BS_ + gridB) {
    int g = (bx - BS_) * 4 + wid;
    if (g >= BS_) return;
    pool_one(itemj_piece, permj, offsj, g, lane, va, vb, itemj_out, g);
  } else {
    int idx = (bx - BS_ - gridB) * 4 + wid;
    if (idx >= BS_) return;
    int pos = *pos_ptr;
    pos = min(max(pos, 0), n_uni - BS_);
    int rr = pos + idx;
    if ((unsigned)user_seg[rr] < (unsigned)BS_) return;
    pool_one(pieces, perm1, offs1, rr, lane, va, vb, itemi_out, idx);
  }
}

// ---- fused latents + BPR scores (VALIDATED r8/r9, verbatim) ----
__global__ __launch_bounds__(1024)
void latpred_kernel(const float* __restrict__ user_rep, const float* __restrict__ itemi,
                    const float* __restrict__ itemj,
                    const float* __restrict__ user_W, const float* __restrict__ user_b,
                    const float* __restrict__ item_W, const float* __restrict__ item_b,
                    float* __restrict__ pred_i, float* __restrict__ pred_j) {
  const int rows0 = blockIdx.x * 8;
  const int t = threadIdx.x;

  __shared__ float4 lAu[8][129], lAi[8][129], lAj[8][129];
  __shared__ float si[8][129], sj[8][129];
  {
    const int r = t >> 7, c = t & 127;
    lAu[r][c] = ((const float4*)user_rep)[(size_t)(rows0 + r) * D4C + c];
    lAi[r][c] = ((const float4*)itemi)[(size_t)(rows0 + r) * D4C + c];
    lAj[r][c] = ((const float4*)itemj)[(size_t)(rows0 + r) * D4C + c];
  }
  __syncthreads();

  const int row = t & 7;
  const int f   = t >> 3;
  const float4* __restrict__ Wu = (const float4*)user_W;
  const float4* __restrict__ Wi = (const float4*)item_W;
  float au = 0.f, ai = 0.f, aj = 0.f;
  for (int k4 = 0; k4 < D4C; ++k4) {
    float4 u = lAu[row][k4];
    float4 i4 = lAi[row][k4];
    float4 j4 = lAj[row][k4];
    float4 wu = Wu[(size_t)f * D4C + k4];
    float4 wi = Wi[(size_t)f * D4C + k4];
    au += u.x * wu.x + u.y * wu.y + u.z * wu.z + u.w * wu.w;
    ai += i4.x * wi.x + i4.y * wi.y + i4.z * wi.z + i4.w * wi.w;
    aj += j4.x * wi.x + j4.y * wi.y + j4.z * wi.z + j4.w * wi.w;
  }
  float lu = au + user_b[f];
  float li = ai + item_b[f];
  float lj = aj + item_b[f];
  si[row][f] = lu * li;
  sj[row][f] = lu * lj;
  __syncthreads();

  const int wid = t >> 6, lane = t & 63;
  if (wid < 8) {
    float v = si[wid][lane] + si[wid][lane + 64];
    v = wave_reduce_sum(v);
    if (lane == 0) pred_i[rows0 + wid] = v;
  } else {
    int r = wid - 8;
    float v = sj[r][lane] + sj[r][lane + 64];
    v = wave_reduce_sum(v);
    if (lane == 0) pred_j[rows0 + r] = v;
  }
}

extern "C" void kernel_launch(void* const* d_in, const int* in_sizes, int n_in,
                              void* d_out, int out_size, void* d_ws, size_t ws_size,
                              hipStream_t stream) {
  const float* user_pooled = (const float*)d_in[0];
  const float* itemj_piece = (const float*)d_in[1];
  const float* Ws1   = (const float*)d_in[2];
  const float* ws2   = (const float*)d_in[3];
  const float* Ws01  = (const float*)d_in[4];
  const float* ws02  = (const float*)d_in[5];
  const float* user_W = (const float*)d_in[6];
  const float* user_b = (const float*)d_in[7];
  const float* item_W = (const float*)d_in[8];
  const float* item_b = (const float*)d_in[9];
  const int* piece_seg = (const int*)d_in[10];
  const int* user_seg  = (const int*)d_in[11];
  const int* itemj_seg = (const int*)d_in[12];
  const int* pos_ptr   = (const int*)d_in[13];

  const int P_U  = in_sizes[10];
  const int NUNI = in_sizes[11];
  const int P_J  = in_sizes[12];

  float* ws = (float*)d_ws;
  float* v0 = ws;                                    // 512
  float* v1 = ws + 512;                              // 512
  float* user_rep = ws + 1024;                       // BS*512
  int* ib = (int*)(user_rep + (size_t)BS_ * D_MODEL);
  int* perm1 = ib;                 ib += P_U;
  int* perm2 = ib;                 ib += NUNI;
  int* permj = ib;                 ib += P_J;
  int* offs1 = ib;                 ib += NUNI + 1;
  int* offs2 = ib;                 ib += BS_ + 1;
  int* offsj = ib;                 ib += BS_ + 1;

  float* outf = (float*)d_out;
  float* itemi_out = outf;
  float* itemj_out = outf + (size_t)BS_ * D_MODEL;
  float* pred_i = outf + 2 * (size_t)BS_ * D_MODEL;
  float* pred_j = pred_i + BS_;

  // L1: all sort-prep + v vectors, ONE ordinary launch (in-block syncs only)
  prep_kernel<<<11, 1024, 0, stream>>>(
      piece_seg, P_U, NUNI, offs1, perm1,
      user_seg, NUNI, BS_, offs2, perm2,
      itemj_seg, P_J, BS_, offsj, permj,
      Ws01, ws02, Ws1, ws2, v0, v1);

  // L2: fused pools (user path + itemj + itemi-fix)
  const int gridB = (BS_ + 3) / 4, gridC = (BS_ + 3) / 4;
  mega_pool_kernel<<<BS_ + gridB + gridC, 256, 0, stream>>>(
      user_pooled, perm1, offs1, perm2, offs2, user_seg, NUNI,
      itemj_piece, permj, offsj, v0, v1,
      user_rep, itemi_out, itemj_out, pos_ptr);

  // L3: latents + scores
  latpred_kernel<<<BS_ / 8, 1024, 0, stream>>>(user_rep, itemi_out, itemj_out,
                                               user_W, user_b, item_W, item_b,
                                               pred_i, pred_j);
}

// Round 12
// 205.567 us; speedup vs baseline: 1.6024x; 1.1507x over previous
//
#include <hip/hip_runtime.h>

#define D_MODEL 512
#define D4C     128   // D_MODEL / 4
#define DA_C    256
#define FACTOR_ 128
#define BS_     4096
#define HALFK   12288  // LDS counter window (48 KB)

__device__ __forceinline__ float wave_reduce_sum(float x) {
#pragma unroll
  for (int o = 32; o; o >>= 1) x += __shfl_xor(x, o, 64);
  return x;
}

// ---- multi-block counting sort (width!) + vvec, ONE ordinary launch ----
// Groups: blocks [0,B1) -> seg1, [B1,B1+B2) -> seg2, [.,+B3) -> seg3, +8 vvec.
// Every sort block counts the FULL seg array into its own LDS window (redundant
// but parallel), scans in-block, then fills only its 1/GB share of elements.
// Global cur[] atomics order intra-segment; cur zeroed by hipMemsetAsync.
// NO grid.sync (r10: ~60us/sync), NO single-block serialization (r11: 160us).
__global__ __launch_bounds__(1024)
void prep2_kernel(const int* __restrict__ seg1, int n1, int k1,
                  int* __restrict__ offs1, int* __restrict__ perm1, int* __restrict__ cur1,
                  const int* __restrict__ seg2, int n2, int k2,
                  int* __restrict__ offs2, int* __restrict__ perm2, int* __restrict__ cur2,
                  const int* __restrict__ seg3, int n3, int k3,
                  int* __restrict__ offs3, int* __restrict__ perm3, int* __restrict__ cur3,
                  const float* __restrict__ Ws01, const float* __restrict__ ws02,
                  const float* __restrict__ Ws1,  const float* __restrict__ ws2,
                  float* __restrict__ v0, float* __restrict__ v1,
                  int B1, int B2, int B3) {
  __shared__ int cntS[HALFK];
  __shared__ int wpre[17];
  __shared__ float vred[8][128];

  const int bx = blockIdx.x, t = threadIdx.x;
  const int lane = t & 63, wid = t >> 6;

  const int* seg; int n, k, gb, GB;
  int *offs, *perm, *cur;
  if (bx < B1)                { gb = bx;            GB = B1; seg = seg1; n = n1; k = k1; offs = offs1; perm = perm1; cur = cur1; }
  else if (bx < B1 + B2)      { gb = bx - B1;       GB = B2; seg = seg2; n = n2; k = k2; offs = offs2; perm = perm2; cur = cur2; }
  else if (bx < B1 + B2 + B3) { gb = bx - B1 - B2;  GB = B3; seg = seg3; n = n3; k = k3; offs = offs3; perm = perm3; cur = cur3; }
  else {
    // ---- vvec: block handles 128 cols of one matrix fully (validated r11) ----
    const int vb = bx - (B1 + B2 + B3);   // 0..7
    const int m = vb >> 2;
    const int c0 = (vb & 3) * 128;
    const float* W  = m ? Ws1 : Ws01;
    const float* w2 = m ? ws2 : ws02;
    const int col = t & 127;
    const int g = t >> 7;                 // 0..7, 32 a-rows each
    float s = 0.f;
    for (int a = g * 32; a < g * 32 + 32; ++a)
      s += w2[a] * W[a * D_MODEL + c0 + col];
    vred[g][col] = s;
    __syncthreads();
    if (t < 128) {
      float acc = 0.f;
#pragma unroll
      for (int q = 0; q < 8; ++q) acc += vred[q][t];
      (m ? v1 : v0)[c0 + t] = acc;
    }
    return;
  }

  int base = 0;
  for (int h0 = 0; h0 < k; h0 += HALFK) {
    const int hk = min(k - h0, HALFK);
    // zero window
    for (int i = t; i < hk; i += 1024) cntS[i] = 0;
    __syncthreads();
    // count FULL array into window (VALUE-DRIVEN; OOR dropped)
    for (int i = t; i < n; i += 1024) {
      int l = seg[i] - h0;
      if ((unsigned)l < (unsigned)hk) atomicAdd(&cntS[l], 1);
    }
    __syncthreads();
    // in-place exclusive scan (globalized with base)
    const int per = (hk + 1023) / 1024;
    const int lo = min(t * per, hk), hi = min(lo + per, hk);
    int s = 0;
    for (int i = lo; i < hi; ++i) s += cntS[i];
    int x = s;
#pragma unroll
    for (int o = 1; o < 64; o <<= 1) {
      int y = __shfl_up(x, o, 64);
      if (lane >= o) x += y;
    }
    if (lane == 63) wpre[wid] = x;
    __syncthreads();
    if (t == 0) {
      int acc = 0;
#pragma unroll
      for (int i2 = 0; i2 < 16; ++i2) { int tmp = wpre[i2]; wpre[i2] = acc; acc += tmp; }
      wpre[16] = acc;   // window total
    }
    __syncthreads();
    int acc = base + wpre[wid] + (x - s);
    for (int i = lo; i < hi; ++i) { int tmp = cntS[i]; cntS[i] = acc; acc += tmp; }
    const int halftot = wpre[16];
    __syncthreads();
    // group leader publishes global offs for mega_pool
    if (gb == 0) {
      for (int i = t; i < hk; i += 1024) offs[h0 + i] = cntS[i];
    }
    // fill THIS block's 1/GB share (cur atomics give intra-seg positions)
    for (int i = gb * 1024 + t; i < n; i += GB * 1024) {
      int sgv = seg[i];
      int l = sgv - h0;
      if ((unsigned)l < (unsigned)hk) {
        int pos = atomicAdd(&cur[sgv], 1);
        perm[cntS[l] + pos] = i;
      }
    }
    base += halftot;
    __syncthreads();
  }
  if (gb == 0 && t == 0) offs[k] = base;
}

// Pool one segment (wave-per-segment gather; VALIDATED r7-r11).
__device__ __forceinline__ void pool_one(const float* __restrict__ X,
                                         const int* __restrict__ perm,
                                         const int* __restrict__ offs, int g, int lane,
                                         float4 va, float4 vb, float* __restrict__ out,
                                         int orow) {
  const float4* __restrict__ X4 = (const float4*)X;
  const int s = offs[g], e = offs[g + 1];
  float4 a0 = make_float4(0.f, 0.f, 0.f, 0.f);
  float4 a1 = make_float4(0.f, 0.f, 0.f, 0.f);
  float z = 0.f;
  for (int p = s; p < e; ++p) {
    int row = perm[p];
    float4 x0 = X4[(size_t)row * D4C + lane * 2];
    float4 x1 = X4[(size_t)row * D4C + lane * 2 + 1];
    float d = x0.x * va.x + x0.y * va.y + x0.z * va.z + x0.w * va.w
            + x1.x * vb.x + x1.y * vb.y + x1.z * vb.z + x1.w * vb.w;
    d = wave_reduce_sum(d);
    float w = expf(d);
    z += w;
    a0.x += w * x0.x; a0.y += w * x0.y; a0.z += w * x0.z; a0.w += w * x0.w;
    a1.x += w * x1.x; a1.y += w * x1.y; a1.z += w * x1.z; a1.w += w * x1.w;
  }
  float inv = (z > 0.f) ? 1.0f / z : 0.f;
  a0.x *= inv; a0.y *= inv; a0.z *= inv; a0.w *= inv;
  a1.x *= inv; a1.y *= inv; a1.z *= inv; a1.w *= inv;
  float4* __restrict__ O4 = (float4*)out;
  O4[(size_t)orow * D4C + lane * 2]     = a0;
  O4[(size_t)orow * D4C + lane * 2 + 1] = a1;
}

// ---- mega pool (VALIDATED r9/r11, verbatim) ----
__global__ __launch_bounds__(256)
void mega_pool_kernel(const float* __restrict__ pieces,
                      const int* __restrict__ perm1, const int* __restrict__ offs1,
                      const int* __restrict__ perm2, const int* __restrict__ offs2,
                      const int* __restrict__ user_seg, int n_uni,
                      const float* __restrict__ itemj_piece,
                      const int* __restrict__ permj, const int* __restrict__ offsj,
                      const float* __restrict__ v0, const float* __restrict__ v1,
                      float* __restrict__ user_rep, float* __restrict__ itemi_out,
                      float* __restrict__ itemj_out, const int* __restrict__ pos_ptr) {
  const int bx = blockIdx.x;
  const int t = threadIdx.x;
  const int wid = t >> 6, lane = t & 63;
  const float4* __restrict__ V0 = (const float4*)v0;

  if (bx < BS_) {
    const float4* __restrict__ V1 = (const float4*)v1;
    const float4* __restrict__ X4 = (const float4*)pieces;
    float4 va0 = V0[lane * 2], vb0 = V0[lane * 2 + 1];
    float4 va1 = V1[lane * 2], vb1 = V1[lane * 2 + 1];
    int pos = *pos_ptr;
    pos = min(max(pos, 0), n_uni - BS_);
    const int u = bx;
    const int s2 = offs2[u], e2 = offs2[u + 1];

    float4 acc0 = make_float4(0.f, 0.f, 0.f, 0.f);
    float4 acc1 = make_float4(0.f, 0.f, 0.f, 0.f);
    float zz = 0.f;
    for (int k = s2 + wid; k < e2; k += 4) {
      const int rr = perm2[k];
      const int s1 = offs1[rr], e1 = offs1[rr + 1];
      float4 r0 = make_float4(0.f, 0.f, 0.f, 0.f);
      float4 r1 = make_float4(0.f, 0.f, 0.f, 0.f);
      float z1 = 0.f;
      for (int p = s1; p < e1; ++p) {
        int prow = perm1[p];
        float4 x0 = X4[(size_t)prow * D4C + lane * 2];
        float4 x1 = X4[(size_t)prow * D4C + lane * 2 + 1];
        float d = x0.x * va0.x + x0.y * va0.y + x0.z * va0.z + x0.w * va0.w
                + x1.x * vb0.x + x1.y * vb0.y + x1.z * vb0.z + x1.w * vb0.w;
        d = wave_reduce_sum(d);
        float w = expf(d);
        z1 += w;
        r0.x += w * x0.x; r0.y += w * x0.y; r0.z += w * x0.z; r0.w += w * x0.w;
        r1.x += w * x1.x; r1.y += w * x1.y; r1.z += w * x1.z; r1.w += w * x1.w;
      }
      float inv1 = (z1 > 0.f) ? 1.0f / z1 : 0.f;
      r0.x *= inv1; r0.y *= inv1; r0.z *= inv1; r0.w *= inv1;
      r1.x *= inv1; r1.y *= inv1; r1.z *= inv1; r1.w *= inv1;
      if (rr >= pos && rr < pos + BS_) {
        float4* __restrict__ O2 = (float4*)itemi_out;
        O2[(size_t)(rr - pos) * D4C + lane * 2]     = r0;
        O2[(size_t)(rr - pos) * D4C + lane * 2 + 1] = r1;
      }
      float d1 = r0.x * va1.x + r0.y * va1.y + r0.z * va1.z + r0.w * va1.w
               + r1.x * vb1.x + r1.y * vb1.y + r1.z * vb1.z + r1.w * vb1.w;
      d1 = wave_reduce_sum(d1);
      float e2w = expf(d1);
      zz += e2w;
      acc0.x += e2w * r0.x; acc0.y += e2w * r0.y;
      acc0.z += e2w * r0.z; acc0.w += e2w * r0.w;
      acc1.x += e2w * r1.x; acc1.y += e2w * r1.y;
      acc1.z += e2w * r1.z; acc1.w += e2w * r1.w;
    }
    __shared__ float4 pbuf[4][130];
    __shared__ float zbuf[4];
    pbuf[wid][lane * 2]     = acc0;
    pbuf[wid][lane * 2 + 1] = acc1;
    if (lane == 0) zbuf[wid] = zz;
    __syncthreads();
    if (wid == 0) {
      float4 A0 = make_float4(0.f, 0.f, 0.f, 0.f);
      float4 A1 = make_float4(0.f, 0.f, 0.f, 0.f);
      float Z = zbuf[0] + zbuf[1] + zbuf[2] + zbuf[3];
#pragma unroll
      for (int w = 0; w < 4; ++w) {
        float4 p0 = pbuf[w][lane * 2], p1 = pbuf[w][lane * 2 + 1];
        A0.x += p0.x; A0.y += p0.y; A0.z += p0.z; A0.w += p0.w;
        A1.x += p1.x; A1.y += p1.y; A1.z += p1.z; A1.w += p1.w;
      }
      float inv = (Z > 0.f) ? 1.0f / Z : 0.f;
      A0.x *= inv; A0.y *= inv; A0.z *= inv; A0.w *= inv;
      A1.x *= inv; A1.y *= inv; A1.z *= inv; A1.w *= inv;
      float4* __restrict__ O4 = (float4*)user_rep;
      O4[(size_t)u * D4C + lane * 2]     = A0;
      O4[(size_t)u * D4C + lane * 2 + 1] = A1;
    }
    return;
  }

  const int gridB = (BS_ + 3) >> 2;
  float4 va = V0[lane * 2], vb = V0[lane * 2 + 1];
  if (bx < BS_ + gridB) {
    int g = (bx - BS_) * 4 + wid;
    if (g >= BS_) return;
    pool_one(itemj_piece, permj, offsj, g, lane, va, vb, itemj_out, g);
  } else {
    int idx = (bx - BS_ - gridB) * 4 + wid;
    if (idx >= BS_) return;
    int pos = *pos_ptr;
    pos = min(max(pos, 0), n_uni - BS_);
    int rr = pos + idx;
    if ((unsigned)user_seg[rr] < (unsigned)BS_) return;
    pool_one(pieces, perm1, offs1, rr, lane, va, vb, itemi_out, idx);
  }
}

// ---- fused latents + BPR scores (VALIDATED r8-r11, verbatim) ----
__global__ __launch_bounds__(1024)
void latpred_kernel(const float* __restrict__ user_rep, const float* __restrict__ itemi,
                    const float* __restrict__ itemj,
                    const float* __restrict__ user_W, const float* __restrict__ user_b,
                    const float* __restrict__ item_W, const float* __restrict__ item_b,
                    float* __restrict__ pred_i, float* __restrict__ pred_j) {
  const int rows0 = blockIdx.x * 8;
  const int t = threadIdx.x;

  __shared__ float4 lAu[8][129], lAi[8][129], lAj[8][129];
  __shared__ float si[8][129], sj[8][129];
  {
    const int r = t >> 7, c = t & 127;
    lAu[r][c] = ((const float4*)user_rep)[(size_t)(rows0 + r) * D4C + c];
    lAi[r][c] = ((const float4*)itemi)[(size_t)(rows0 + r) * D4C + c];
    lAj[r][c] = ((const float4*)itemj)[(size_t)(rows0 + r) * D4C + c];
  }
  __syncthreads();

  const int row = t & 7;
  const int f   = t >> 3;
  const float4* __restrict__ Wu = (const float4*)user_W;
  const float4* __restrict__ Wi = (const float4*)item_W;
  float au = 0.f, ai = 0.f, aj = 0.f;
  for (int k4 = 0; k4 < D4C; ++k4) {
    float4 u = lAu[row][k4];
    float4 i4 = lAi[row][k4];
    float4 j4 = lAj[row][k4];
    float4 wu = Wu[(size_t)f * D4C + k4];
    float4 wi = Wi[(size_t)f * D4C + k4];
    au += u.x * wu.x + u.y * wu.y + u.z * wu.z + u.w * wu.w;
    ai += i4.x * wi.x + i4.y * wi.y + i4.z * wi.z + i4.w * wi.w;
    aj += j4.x * wi.x + j4.y * wi.y + j4.z * wi.z + j4.w * wi.w;
  }
  float lu = au + user_b[f];
  float li = ai + item_b[f];
  float lj = aj + item_b[f];
  si[row][f] = lu * li;
  sj[row][f] = lu * lj;
  __syncthreads();

  const int wid = t >> 6, lane = t & 63;
  if (wid < 8) {
    float v = si[wid][lane] + si[wid][lane + 64];
    v = wave_reduce_sum(v);
    if (lane == 0) pred_i[rows0 + wid] = v;
  } else {
    int r = wid - 8;
    float v = sj[r][lane] + sj[r][lane + 64];
    v = wave_reduce_sum(v);
    if (lane == 0) pred_j[rows0 + r] = v;
  }
}

extern "C" void kernel_launch(void* const* d_in, const int* in_sizes, int n_in,
                              void* d_out, int out_size, void* d_ws, size_t ws_size,
                              hipStream_t stream) {
  const float* user_pooled = (const float*)d_in[0];
  const float* itemj_piece = (const float*)d_in[1];
  const float* Ws1   = (const float*)d_in[2];
  const float* ws2   = (const float*)d_in[3];
  const float* Ws01  = (const float*)d_in[4];
  const float* ws02  = (const float*)d_in[5];
  const float* user_W = (const float*)d_in[6];
  const float* user_b = (const float*)d_in[7];
  const float* item_W = (const float*)d_in[8];
  const float* item_b = (const float*)d_in[9];
  const int* piece_seg = (const int*)d_in[10];
  const int* user_seg  = (const int*)d_in[11];
  const int* itemj_seg = (const int*)d_in[12];
  const int* pos_ptr   = (const int*)d_in[13];

  const int P_U  = in_sizes[10];
  const int NUNI = in_sizes[11];
  const int P_J  = in_sizes[12];

  float* ws = (float*)d_ws;
  float* v0 = ws;                                    // 512
  float* v1 = ws + 512;                              // 512
  float* user_rep = ws + 1024;                       // BS*512
  int* ib = (int*)(user_rep + (size_t)BS_ * D_MODEL);
  int* perm1 = ib;                 ib += P_U;
  int* perm2 = ib;                 ib += NUNI;
  int* permj = ib;                 ib += P_J;
  int* offs1 = ib;                 ib += NUNI + 1;
  int* offs2 = ib;                 ib += BS_ + 1;
  int* offsj = ib;                 ib += BS_ + 1;
  int* cur1  = ib;                 ib += NUNI;   // cur1/2/3 contiguous: one memset
  int* cur2  = ib;                 ib += BS_;
  int* cur3  = ib;                 ib += BS_;

  float* outf = (float*)d_out;
  float* itemi_out = outf;
  float* itemj_out = outf + (size_t)BS_ * D_MODEL;
  float* pred_i = outf + 2 * (size_t)BS_ * D_MODEL;
  float* pred_j = pred_i + BS_;

  // L0: DMA-zero the cur counters (graph-capture-safe async memset)
  hipMemsetAsync(cur1, 0, (size_t)(NUNI + BS_ + BS_) * sizeof(int), stream);

  // L1: all sort-prep + v vectors, ONE wide launch (block-local syncs only)
  const int B1 = 48, B2 = 8, B3 = 8;
  prep2_kernel<<<B1 + B2 + B3 + 8, 1024, 0, stream>>>(
      piece_seg, P_U, NUNI, offs1, perm1, cur1,
      user_seg, NUNI, BS_, offs2, perm2, cur2,
      itemj_seg, P_J, BS_, offsj, permj, cur3,
      Ws01, ws02, Ws1, ws2, v0, v1, B1, B2, B3);

  // L2: fused pools (user path + itemj + itemi-fix)
  const int gridB = (BS_ + 3) / 4, gridC = (BS_ + 3) / 4;
  mega_pool_kernel<<<BS_ + gridB + gridC, 256, 0, stream>>>(
      user_pooled, perm1, offs1, perm2, offs2, user_seg, NUNI,
      itemj_piece, permj, offsj, v0, v1,
      user_rep, itemi_out, itemj_out, pos_ptr);

  // L3: latents + scores
  latpred_kernel<<<BS_ / 8, 1024, 0, stream>>>(user_rep, itemi_out, itemj_out,
                                               user_W, user_b, item_W, item_b,
                                               pred_i, pred_j);
}

// Round 13
// 199.842 us; speedup vs baseline: 1.6483x; 1.0286x over previous
//
#include <hip/hip_runtime.h>

#define D_MODEL 512
#define D4C     128   // D_MODEL / 4
#define DA_C    256
#define FACTOR_ 128
#define BS_     4096
#define PRE_    4      // register-prefetch depth (data: np == 4 typical)

__device__ __forceinline__ float wave_reduce_sum(float x) {
#pragma unroll
  for (int o = 32; o; o >>= 1) x += __shfl_xor(x, o, 64);
  return x;
}

// ---- L1: fused zero (cnt/cur) + vvec partials (VALIDATED r9) ----
__global__ __launch_bounds__(256)
void prep_kernel(int* __restrict__ zbase, int n_zero,
                 const float* __restrict__ Ws01, const float* __restrict__ ws02,
                 const float* __restrict__ Ws1,  const float* __restrict__ ws2,
                 float* __restrict__ part) {
  const int bx = blockIdx.x;
  const int t = threadIdx.x;
  if (bx < 64) {
    int i = bx * 256 + t;
    for (; i < n_zero; i += 64 * 256) zbase[i] = 0;
  } else {
    const int r = bx - 64;            // 0..15
    const int m = r >> 3, c = r & 7;
    const float* W  = m ? Ws1 : Ws01;
    const float* w2 = m ? ws2 : ws02;
    const int a0 = c * 32;
    float s0 = 0.f, s1 = 0.f;
#pragma unroll 8
    for (int a = a0; a < a0 + 32; ++a) {
      float wa = w2[a];
      s0 += wa * W[a * D_MODEL + t];
      s1 += wa * W[a * D_MODEL + t + 256];
    }
    part[(m * 8 + c) * 512 + t] = s0;
    part[(m * 8 + c) * 512 + t + 256] = s1;
  }
}

// ---- L2: count histograms (3 arrays) + vvec reduce (VALIDATED r9) ----
__global__ __launch_bounds__(256)
void count_red_kernel(const int* __restrict__ s1, int n1, int k1, int* __restrict__ c1,
                      const int* __restrict__ s2, int n2, int k2, int* __restrict__ c2,
                      const int* __restrict__ s3, int n3, int k3, int* __restrict__ c3,
                      const float* __restrict__ part, float* __restrict__ v0,
                      float* __restrict__ v1) {
  const int a = blockIdx.y;
  if (a == 3) {
    if (blockIdx.x == 0) {
#pragma unroll
      for (int k = 0; k < 4; ++k) {
        int idx = k * 256 + threadIdx.x;       // 0..1023
        int m = idx >> 9, col = idx & 511;
        float s = 0.f;
#pragma unroll
        for (int c = 0; c < 8; ++c) s += part[(m * 8 + c) * 512 + col];
        (m ? v1 : v0)[col] = s;
      }
    }
    return;
  }
  const int* seg = a == 0 ? s1 : (a == 1 ? s2 : s3);
  int n = a == 0 ? n1 : (a == 1 ? n2 : n3);
  int nseg = a == 0 ? k1 : (a == 1 ? k2 : k3);
  int* cnt = a == 0 ? c1 : (a == 1 ? c2 : c3);
  int i = blockIdx.x * 256 + threadIdx.x;
  int stride = gridDim.x * 256;
  for (; i < n; i += stride) {
    int sg = seg[i];
    if ((unsigned)sg < (unsigned)nseg) atomicAdd(&cnt[sg], 1);
  }
}

// ---- L3: parallel exclusive scan, 3 arrays (VALIDATED r9) ----
__global__ __launch_bounds__(1024)
void scan3_kernel(const int* __restrict__ c1, int n1, int* __restrict__ o1,
                  const int* __restrict__ c2, int n2, int* __restrict__ o2,
                  const int* __restrict__ c3, int n3, int* __restrict__ o3) {
  const int b = blockIdx.x;
  const int* cnt = b == 0 ? c1 : (b == 1 ? c2 : c3);
  int n = b == 0 ? n1 : (b == 1 ? n2 : n3);
  int* offs = b == 0 ? o1 : (b == 1 ? o2 : o3);
  const int t = threadIdx.x;
  const int lane = t & 63, wid = t >> 6;
  __shared__ int wsum[16];
  const int per = (n + 1023) / 1024;
  const int lo = min(t * per, n);
  const int hi = min(lo + per, n);
  int s = 0;
  for (int i = lo; i < hi; ++i) s += cnt[i];
  int x = s;
#pragma unroll
  for (int o = 1; o < 64; o <<= 1) {
    int y = __shfl_up(x, o, 64);
    if (lane >= o) x += y;
  }
  if (lane == 63) wsum[wid] = x;
  __syncthreads();
  if (t == 0) {
    int acc = 0;
#pragma unroll
    for (int i = 0; i < 16; ++i) { int tmp = wsum[i]; wsum[i] = acc; acc += tmp; }
    offs[n] = acc;
  }
  __syncthreads();
  int acc = wsum[wid] + (x - s);
  for (int i = lo; i < hi; ++i) { offs[i] = acc; acc += cnt[i]; }
}

// ---- L4: fill permutations (VALIDATED r9) ----
__global__ __launch_bounds__(256)
void fill3_kernel(const int* __restrict__ s1, int n1, int k1, const int* __restrict__ of1,
                  int* __restrict__ cu1, int* __restrict__ p1,
                  const int* __restrict__ s2, int n2, int k2, const int* __restrict__ of2,
                  int* __restrict__ cu2, int* __restrict__ p2,
                  const int* __restrict__ s3, int n3, int k3, const int* __restrict__ of3,
                  int* __restrict__ cu3, int* __restrict__ p3) {
  const int a = blockIdx.y;
  const int* seg = a == 0 ? s1 : (a == 1 ? s2 : s3);
  int n = a == 0 ? n1 : (a == 1 ? n2 : n3);
  int nseg = a == 0 ? k1 : (a == 1 ? k2 : k3);
  const int* offs = a == 0 ? of1 : (a == 1 ? of2 : of3);
  int* cur = a == 0 ? cu1 : (a == 1 ? cu2 : cu3);
  int* perm = a == 0 ? p1 : (a == 1 ? p2 : p3);
  int i = blockIdx.x * 256 + threadIdx.x;
  int stride = gridDim.x * 256;
  for (; i < n; i += stride) {
    int sg = seg[i];
    if ((unsigned)sg < (unsigned)nseg) {
      int pos = atomicAdd(&cur[sg], 1);
      perm[offs[sg] + pos] = i;
    }
  }
}

// Pool one segment with PRE_-deep register prefetch (statically unrolled so
// arrays stay in VGPRs — rule: no runtime-indexed local arrays).
__device__ __forceinline__ void pool_one(const float* __restrict__ X,
                                         const int* __restrict__ perm,
                                         const int* __restrict__ offs, int g, int lane,
                                         float4 va, float4 vb, float* __restrict__ out,
                                         int orow) {
  const float4* __restrict__ X4 = (const float4*)X;
  const int s = offs[g], e = offs[g + 1];
  const int np = e - s;
  const int npre = np < PRE_ ? np : PRE_;
  float4 a0 = make_float4(0.f, 0.f, 0.f, 0.f);
  float4 a1 = make_float4(0.f, 0.f, 0.f, 0.f);
  float z = 0.f;

  float4 px0[PRE_], px1[PRE_];
#pragma unroll
  for (int p = 0; p < PRE_; ++p) {     // independent loads issue together (MLP=4)
    if (p < npre) {
      int row = perm[s + p];
      px0[p] = X4[(size_t)row * D4C + lane * 2];
      px1[p] = X4[(size_t)row * D4C + lane * 2 + 1];
    }
  }
#pragma unroll
  for (int p = 0; p < PRE_; ++p) {
    if (p < npre) {
      float d = px0[p].x * va.x + px0[p].y * va.y + px0[p].z * va.z + px0[p].w * va.w
              + px1[p].x * vb.x + px1[p].y * vb.y + px1[p].z * vb.z + px1[p].w * vb.w;
      d = wave_reduce_sum(d);
      float w = expf(d);
      z += w;
      a0.x += w * px0[p].x; a0.y += w * px0[p].y; a0.z += w * px0[p].z; a0.w += w * px0[p].w;
      a1.x += w * px1[p].x; a1.y += w * px1[p].y; a1.z += w * px1[p].z; a1.w += w * px1[p].w;
    }
  }
  for (int p = s + npre; p < e; ++p) {  // rare tail (np > 4)
    int row = perm[p];
    float4 x0 = X4[(size_t)row * D4C + lane * 2];
    float4 x1 = X4[(size_t)row * D4C + lane * 2 + 1];
    float d = x0.x * va.x + x0.y * va.y + x0.z * va.z + x0.w * va.w
            + x1.x * vb.x + x1.y * vb.y + x1.z * vb.z + x1.w * vb.w;
    d = wave_reduce_sum(d);
    float w = expf(d);
    z += w;
    a0.x += w * x0.x; a0.y += w * x0.y; a0.z += w * x0.z; a0.w += w * x0.w;
    a1.x += w * x1.x; a1.y += w * x1.y; a1.z += w * x1.z; a1.w += w * x1.w;
  }

  float inv = (z > 0.f) ? 1.0f / z : 0.f;
  a0.x *= inv; a0.y *= inv; a0.z *= inv; a0.w *= inv;
  a1.x *= inv; a1.y *= inv; a1.z *= inv; a1.w *= inv;
  float4* __restrict__ O4 = (float4*)out;
  O4[(size_t)orow * D4C + lane * 2]     = a0;
  O4[(size_t)orow * D4C + lane * 2 + 1] = a1;
}

// ---- L5: mega pool (r9 structure; role-A inner loop now prefetched) ----
__global__ __launch_bounds__(256)
void mega_pool_kernel(const float* __restrict__ pieces,
                      const int* __restrict__ perm1, const int* __restrict__ offs1,
                      const int* __restrict__ perm2, const int* __restrict__ offs2,
                      const int* __restrict__ user_seg, int n_uni,
                      const float* __restrict__ itemj_piece,
                      const int* __restrict__ permj, const int* __restrict__ offsj,
                      const float* __restrict__ v0, const float* __restrict__ v1,
                      float* __restrict__ user_rep, float* __restrict__ itemi_out,
                      float* __restrict__ itemj_out, const int* __restrict__ pos_ptr) {
  const int bx = blockIdx.x;
  const int t = threadIdx.x;
  const int wid = t >> 6, lane = t & 63;
  const float4* __restrict__ V0 = (const float4*)v0;

  if (bx < BS_) {
    const float4* __restrict__ V1 = (const float4*)v1;
    const float4* __restrict__ X4 = (const float4*)pieces;
    float4 va0 = V0[lane * 2], vb0 = V0[lane * 2 + 1];
    float4 va1 = V1[lane * 2], vb1 = V1[lane * 2 + 1];
    int pos = *pos_ptr;
    pos = min(max(pos, 0), n_uni - BS_);
    const int u = bx;
    const int s2 = offs2[u], e2 = offs2[u + 1];

    float4 acc0 = make_float4(0.f, 0.f, 0.f, 0.f);
    float4 acc1 = make_float4(0.f, 0.f, 0.f, 0.f);
    float zz = 0.f;
    for (int k = s2 + wid; k < e2; k += 4) {
      const int rr = perm2[k];
      const int s1 = offs1[rr], e1 = offs1[rr + 1];
      const int np = e1 - s1;
      const int npre = np < PRE_ ? np : PRE_;
      float4 r0 = make_float4(0.f, 0.f, 0.f, 0.f);
      float4 r1 = make_float4(0.f, 0.f, 0.f, 0.f);
      float z1 = 0.f;

      float4 px0[PRE_], px1[PRE_];
#pragma unroll
      for (int p = 0; p < PRE_; ++p) {   // 4 independent 512B row loads (MLP=4)
        if (p < npre) {
          int prow = perm1[s1 + p];
          px0[p] = X4[(size_t)prow * D4C + lane * 2];
          px1[p] = X4[(size_t)prow * D4C + lane * 2 + 1];
        }
      }
#pragma unroll
      for (int p = 0; p < PRE_; ++p) {
        if (p < npre) {
          float d = px0[p].x * va0.x + px0[p].y * va0.y + px0[p].z * va0.z + px0[p].w * va0.w
                  + px1[p].x * vb0.x + px1[p].y * vb0.y + px1[p].z * vb0.z + px1[p].w * vb0.w;
          d = wave_reduce_sum(d);
          float w = expf(d);
          z1 += w;
          r0.x += w * px0[p].x; r0.y += w * px0[p].y; r0.z += w * px0[p].z; r0.w += w * px0[p].w;
          r1.x += w * px1[p].x; r1.y += w * px1[p].y; r1.z += w * px1[p].z; r1.w += w * px1[p].w;
        }
      }
      for (int p = s1 + npre; p < e1; ++p) {  // rare tail
        int prow = perm1[p];
        float4 x0 = X4[(size_t)prow * D4C + lane * 2];
        float4 x1 = X4[(size_t)prow * D4C + lane * 2 + 1];
        float d = x0.x * va0.x + x0.y * va0.y + x0.z * va0.z + x0.w * va0.w
                + x1.x * vb0.x + x1.y * vb0.y + x1.z * vb0.z + x1.w * vb0.w;
        d = wave_reduce_sum(d);
        float w = expf(d);
        z1 += w;
        r0.x += w * x0.x; r0.y += w * x0.y; r0.z += w * x0.z; r0.w += w * x0.w;
        r1.x += w * x1.x; r1.y += w * x1.y; r1.z += w * x1.z; r1.w += w * x1.w;
      }

      float inv1 = (z1 > 0.f) ? 1.0f / z1 : 0.f;
      r0.x *= inv1; r0.y *= inv1; r0.z *= inv1; r0.w *= inv1;
      r1.x *= inv1; r1.y *= inv1; r1.z *= inv1; r1.w *= inv1;
      if (rr >= pos && rr < pos + BS_) {
        float4* __restrict__ O2 = (float4*)itemi_out;
        O2[(size_t)(rr - pos) * D4C + lane * 2]     = r0;
        O2[(size_t)(rr - pos) * D4C + lane * 2 + 1] = r1;
      }
      float d1 = r0.x * va1.x + r0.y * va1.y + r0.z * va1.z + r0.w * va1.w
               + r1.x * vb1.x + r1.y * vb1.y + r1.z * vb1.z + r1.w * vb1.w;
      d1 = wave_reduce_sum(d1);
      float e2w = expf(d1);
      zz += e2w;
      acc0.x += e2w * r0.x; acc0.y += e2w * r0.y;
      acc0.z += e2w * r0.z; acc0.w += e2w * r0.w;
      acc1.x += e2w * r1.x; acc1.y += e2w * r1.y;
      acc1.z += e2w * r1.z; acc1.w += e2w * r1.w;
    }
    __shared__ float4 pbuf[4][130];
    __shared__ float zbuf[4];
    pbuf[wid][lane * 2]     = acc0;
    pbuf[wid][lane * 2 + 1] = acc1;
    if (lane == 0) zbuf[wid] = zz;
    __syncthreads();
    if (wid == 0) {
      float4 A0 = make_float4(0.f, 0.f, 0.f, 0.f);
      float4 A1 = make_float4(0.f, 0.f, 0.f, 0.f);
      float Z = zbuf[0] + zbuf[1] + zbuf[2] + zbuf[3];
#pragma unroll
      for (int w = 0; w < 4; ++w) {
        float4 p0 = pbuf[w][lane * 2], p1 = pbuf[w][lane * 2 + 1];
        A0.x += p0.x; A0.y += p0.y; A0.z += p0.z; A0.w += p0.w;
        A1.x += p1.x; A1.y += p1.y; A1.z += p1.z; A1.w += p1.w;
      }
      float inv = (Z > 0.f) ? 1.0f / Z : 0.f;
      A0.x *= inv; A0.y *= inv; A0.z *= inv; A0.w *= inv;
      A1.x *= inv; A1.y *= inv; A1.z *= inv; A1.w *= inv;
      float4* __restrict__ O4 = (float4*)user_rep;
      O4[(size_t)u * D4C + lane * 2]     = A0;
      O4[(size_t)u * D4C + lane * 2 + 1] = A1;
    }
    return;
  }

  const int gridB = (BS_ + 3) >> 2;
  float4 va = V0[lane * 2], vb = V0[lane * 2 + 1];
  if (bx < BS_ + gridB) {
    int g = (bx - BS_) * 4 + wid;
    if (g >= BS_) return;
    pool_one(itemj_piece, permj, offsj, g, lane, va, vb, itemj_out, g);
  } else {
    int idx = (bx - BS_ - gridB) * 4 + wid;
    if (idx >= BS_) return;
    int pos = *pos_ptr;
    pos = min(max(pos, 0), n_uni - BS_);
    int rr = pos + idx;
    if ((unsigned)user_seg[rr] < (unsigned)BS_) return;
    pool_one(pieces, perm1, offs1, rr, lane, va, vb, itemi_out, idx);
  }
}

// ---- L6: fused latents + BPR scores (VALIDATED r8-r12, verbatim) ----
__global__ __launch_bounds__(1024)
void latpred_kernel(const float* __restrict__ user_rep, const float* __restrict__ itemi,
                    const float* __restrict__ itemj,
                    const float* __restrict__ user_W, const float* __restrict__ user_b,
                    const float* __restrict__ item_W, const float* __restrict__ item_b,
                    float* __restrict__ pred_i, float* __restrict__ pred_j) {
  const int rows0 = blockIdx.x * 8;
  const int t = threadIdx.x;

  __shared__ float4 lAu[8][129], lAi[8][129], lAj[8][129];
  __shared__ float si[8][129], sj[8][129];
  {
    const int r = t >> 7, c = t & 127;
    lAu[r][c] = ((const float4*)user_rep)[(size_t)(rows0 + r) * D4C + c];
    lAi[r][c] = ((const float4*)itemi)[(size_t)(rows0 + r) * D4C + c];
    lAj[r][c] = ((const float4*)itemj)[(size_t)(rows0 + r) * D4C + c];
  }
  __syncthreads();

  const int row = t & 7;
  const int f   = t >> 3;
  const float4* __restrict__ Wu = (const float4*)user_W;
  const float4* __restrict__ Wi = (const float4*)item_W;
  float au = 0.f, ai = 0.f, aj = 0.f;
  for (int k4 = 0; k4 < D4C; ++k4) {
    float4 u = lAu[row][k4];
    float4 i4 = lAi[row][k4];
    float4 j4 = lAj[row][k4];
    float4 wu = Wu[(size_t)f * D4C + k4];
    float4 wi = Wi[(size_t)f * D4C + k4];
    au += u.x * wu.x + u.y * wu.y + u.z * wu.z + u.w * wu.w;
    ai += i4.x * wi.x + i4.y * wi.y + i4.z * wi.z + i4.w * wi.w;
    aj += j4.x * wi.x + j4.y * wi.y + j4.z * wi.z + j4.w * wi.w;
  }
  float lu = au + user_b[f];
  float li = ai + item_b[f];
  float lj = aj + item_b[f];
  si[row][f] = lu * li;
  sj[row][f] = lu * lj;
  __syncthreads();

  const int wid = t >> 6, lane = t & 63;
  if (wid < 8) {
    float v = si[wid][lane] + si[wid][lane + 64];
    v = wave_reduce_sum(v);
    if (lane == 0) pred_i[rows0 + wid] = v;
  } else {
    int r = wid - 8;
    float v = sj[r][lane] + sj[r][lane + 64];
    v = wave_reduce_sum(v);
    if (lane == 0) pred_j[rows0 + r] = v;
  }
}

extern "C" void kernel_launch(void* const* d_in, const int* in_sizes, int n_in,
                              void* d_out, int out_size, void* d_ws, size_t ws_size,
                              hipStream_t stream) {
  const float* user_pooled = (const float*)d_in[0];
  const float* itemj_piece = (const float*)d_in[1];
  const float* Ws1   = (const float*)d_in[2];
  const float* ws2   = (const float*)d_in[3];
  const float* Ws01  = (const float*)d_in[4];
  const float* ws02  = (const float*)d_in[5];
  const float* user_W = (const float*)d_in[6];
  const float* user_b = (const float*)d_in[7];
  const float* item_W = (const float*)d_in[8];
  const float* item_b = (const float*)d_in[9];
  const int* piece_seg = (const int*)d_in[10];
  const int* user_seg  = (const int*)d_in[11];
  const int* itemj_seg = (const int*)d_in[12];
  const int* pos_ptr   = (const int*)d_in[13];

  const int P_U  = in_sizes[10];
  const int NUNI = in_sizes[11];
  const int P_J  = in_sizes[12];

  float* ws = (float*)d_ws;
  float* v0 = ws;                                    // 512
  float* v1 = ws + 512;                              // 512
  float* vpart = ws + 1024;                          // 8192
  float* user_rep = vpart + 8192;                    // BS*512
  int* ib = (int*)(user_rep + (size_t)BS_ * D_MODEL);
  int* perm1 = ib;                 ib += P_U;
  int* perm2 = ib;                 ib += NUNI;
  int* permj = ib;                 ib += P_J;
  int* offs1 = ib;                 ib += NUNI + 1;
  int* offs2 = ib;                 ib += BS_ + 1;
  int* offsj = ib;                 ib += BS_ + 1;
  int* cnt1  = ib;                 ib += NUNI;   // cnt*/cur* contiguous: one zero
  int* cnt2  = ib;                 ib += BS_;
  int* cntj  = ib;                 ib += BS_;
  int* cur1  = ib;                 ib += NUNI;
  int* cur2  = ib;                 ib += BS_;
  int* curj  = ib;                 ib += BS_;
  const int n_zero = 2 * (NUNI + BS_ + BS_);

  float* outf = (float*)d_out;
  float* itemi_out = outf;
  float* itemj_out = outf + (size_t)BS_ * D_MODEL;
  float* pred_i = outf + 2 * (size_t)BS_ * D_MODEL;
  float* pred_j = pred_i + BS_;

  // L1: zero + vvec partials        (r9-proven prep chain)
  prep_kernel<<<80, 256, 0, stream>>>(cnt1, n_zero, Ws01, ws02, Ws1, ws2, vpart);
  // L2: histograms + vvec reduce
  count_red_kernel<<<dim3(64, 4), 256, 0, stream>>>(piece_seg, P_U, NUNI, cnt1,
                                                    user_seg, NUNI, BS_, cnt2,
                                                    itemj_seg, P_J, BS_, cntj,
                                                    vpart, v0, v1);
  // L3: scans
  scan3_kernel<<<3, 1024, 0, stream>>>(cnt1, NUNI, offs1, cnt2, BS_, offs2,
                                       cntj, BS_, offsj);
  // L4: permutations
  fill3_kernel<<<dim3(64, 3), 256, 0, stream>>>(
      piece_seg, P_U, NUNI, offs1, cur1, perm1,
      user_seg, NUNI, BS_, offs2, cur2, perm2,
      itemj_seg, P_J, BS_, offsj, curj, permj);
  // L5: fused pools (prefetched inner loops)
  const int gridB = (BS_ + 3) / 4, gridC = (BS_ + 3) / 4;
  mega_pool_kernel<<<BS_ + gridB + gridC, 256, 0, stream>>>(
      user_pooled, perm1, offs1, perm2, offs2, user_seg, NUNI,
      itemj_piece, permj, offsj, v0, v1,
      user_rep, itemi_out, itemj_out, pos_ptr);
  // L6: latents + scores
  latpred_kernel<<<BS_ / 8, 1024, 0, stream>>>(user_rep, itemi_out, itemj_out,
                                               user_W, user_b, item_W, item_b,
                                               pred_i, pred_j);
}

// Round 14
// 168.735 us; speedup vs baseline: 1.9521x; 1.1844x over previous
//
#include <hip/hip_runtime.h>

#define D_MODEL 512
#define D4C     128   // D_MODEL / 4
#define DA_C    256
#define FACTOR_ 128
#define BS_     4096
#define WIN_    4096   // value-window width for the block-local counting sort

__device__ __forceinline__ float wave_reduce_sum(float x) {
#pragma unroll
  for (int o = 32; o; o >>= 1) x += __shfl_xor(x, o, 64);
  return x;
}
__device__ __forceinline__ int wave_reduce_sum_i(int x) {
#pragma unroll
  for (int o = 32; o; o >>= 1) x += __shfl_xor(x, o, 64);
  return x;
}

// ---- L1: ALL prep in ONE launch, zero cross-block dependencies ----
// Sort blocks: each owns value-window [lo,hi) of one seg array. Per block:
//   count full array into LDS hist (+ scalar below-count -> global base),
//   in-LDS scan -> offs, re-pass to fill perm via LDS cursors.
// (VALUE-DRIVEN: seg content only; OOR values dropped = JAX semantics.)
// vvec blocks: v = W1^T w2 (r11-validated branch).
__global__ __launch_bounds__(1024)
void prep_all_kernel(const int* __restrict__ seg1, int n1, int k1,
                     int* __restrict__ offs1, int* __restrict__ perm1,
                     const int* __restrict__ seg2, int n2, int k2,
                     int* __restrict__ offs2, int* __restrict__ perm2,
                     const int* __restrict__ seg3, int n3, int k3,
                     int* __restrict__ offs3, int* __restrict__ perm3,
                     const float* __restrict__ Ws01, const float* __restrict__ ws02,
                     const float* __restrict__ Ws1,  const float* __restrict__ ws2,
                     float* __restrict__ v0, float* __restrict__ v1, int nw1) {
  __shared__ int hist[WIN_];     // 16 KB: counts, then cursors
  __shared__ int obase[WIN_];    // 16 KB: scanned global offsets per bin
  __shared__ int wpre[17];
  __shared__ int below_sh[16];
  __shared__ float vred[8][128]; // 4 KB

  const int bx = blockIdx.x, t = threadIdx.x;
  const int lane = t & 63, wid = t >> 6;
  const int nsort = nw1 + 2;

  if (bx < nsort) {
    const int* seg; int n, k, lo, hi;
    int *offs, *perm;
    if (bx < nw1)      { seg = seg1; n = n1; k = k1; offs = offs1; perm = perm1;
                         lo = bx * WIN_; hi = min(lo + WIN_, k); }
    else if (bx == nw1){ seg = seg2; n = n2; k = k2; offs = offs2; perm = perm2;
                         lo = 0; hi = k; }
    else               { seg = seg3; n = n3; k = k3; offs = offs3; perm = perm3;
                         lo = 0; hi = k; }
    const int wk = hi - lo;

    for (int i = t; i < wk; i += 1024) hist[i] = 0;
    __syncthreads();

    // pass 1: window histogram + below-count (base, computed block-locally)
    int below = 0;
    for (int i = t; i < n; i += 1024) {
      unsigned uv = (unsigned)seg[i];
      if (uv < (unsigned)lo) below++;                    // negatives -> huge, excluded
      else { unsigned l = uv - (unsigned)lo;
             if (l < (unsigned)wk) atomicAdd(&hist[l], 1); }  // >=k excluded
    }
    below = wave_reduce_sum_i(below);
    if (lane == 0) below_sh[wid] = below;
    __syncthreads();
    int base = 0;
#pragma unroll
    for (int i = 0; i < 16; ++i) base += below_sh[i];

    // in-LDS exclusive scan of hist -> obase (+ base), publish global offs
    const int per = (wk + 1023) / 1024;
    const int slo = min(t * per, wk), shi = min(slo + per, wk);
    int s = 0;
    for (int i = slo; i < shi; ++i) s += hist[i];
    int x = s;
#pragma unroll
    for (int o = 1; o < 64; o <<= 1) {
      int y = __shfl_up(x, o, 64);
      if (lane >= o) x += y;
    }
    if (lane == 63) wpre[wid] = x;
    __syncthreads();
    if (t == 0) {
      int acc = 0;
#pragma unroll
      for (int i = 0; i < 16; ++i) { int tmp = wpre[i]; wpre[i] = acc; acc += tmp; }
      wpre[16] = acc;
    }
    __syncthreads();
    int acc = base + wpre[wid] + (x - s);
    for (int i = slo; i < shi; ++i) {
      obase[i] = acc;
      offs[lo + i] = acc;
      acc += hist[i];
    }
    if (hi == k && t == 0) offs[k] = base + wpre[16];
    __syncthreads();

    // re-zero hist as cursors, then fill this window's perm entries
    for (int i = t; i < wk; i += 1024) hist[i] = 0;
    __syncthreads();
    for (int i = t; i < n; i += 1024) {
      unsigned uv = (unsigned)seg[i];
      if (uv >= (unsigned)lo) {
        unsigned l = uv - (unsigned)lo;
        if (l < (unsigned)wk) {
          int pos = atomicAdd(&hist[l], 1);
          perm[obase[l] + pos] = i;
        }
      }
    }
    return;
  }

  // ---- vvec: 8 blocks, each 128 cols of one matrix (validated r11/r12) ----
  const int vb = bx - nsort;            // 0..7
  const int m = vb >> 2;
  const int c0 = (vb & 3) * 128;
  const float* W  = m ? Ws1 : Ws01;
  const float* w2 = m ? ws2 : ws02;
  const int col = t & 127;
  const int g = t >> 7;                 // 0..7, 32 a-rows each
  float s = 0.f;
  for (int a = g * 32; a < g * 32 + 32; ++a)
    s += w2[a] * W[a * D_MODEL + c0 + col];
  vred[g][col] = s;
  __syncthreads();
  if (t < 128) {
    float acc = 0.f;
#pragma unroll
    for (int q = 0; q < 8; ++q) acc += vred[q][t];
    (m ? v1 : v0)[c0 + t] = acc;
  }
}

// Pool one segment (wave-per-segment gather; VALIDATED r7-r13, r9 form).
__device__ __forceinline__ void pool_one(const float* __restrict__ X,
                                         const int* __restrict__ perm,
                                         const int* __restrict__ offs, int g, int lane,
                                         float4 va, float4 vb, float* __restrict__ out,
                                         int orow) {
  const float4* __restrict__ X4 = (const float4*)X;
  const int s = offs[g], e = offs[g + 1];
  float4 a0 = make_float4(0.f, 0.f, 0.f, 0.f);
  float4 a1 = make_float4(0.f, 0.f, 0.f, 0.f);
  float z = 0.f;
  for (int p = s; p < e; ++p) {
    int row = perm[p];
    float4 x0 = X4[(size_t)row * D4C + lane * 2];
    float4 x1 = X4[(size_t)row * D4C + lane * 2 + 1];
    float d = x0.x * va.x + x0.y * va.y + x0.z * va.z + x0.w * va.w
            + x1.x * vb.x + x1.y * vb.y + x1.z * vb.z + x1.w * vb.w;
    d = wave_reduce_sum(d);
    float w = expf(d);
    z += w;
    a0.x += w * x0.x; a0.y += w * x0.y; a0.z += w * x0.z; a0.w += w * x0.w;
    a1.x += w * x1.x; a1.y += w * x1.y; a1.z += w * x1.z; a1.w += w * x1.w;
  }
  float inv = (z > 0.f) ? 1.0f / z : 0.f;
  a0.x *= inv; a0.y *= inv; a0.z *= inv; a0.w *= inv;
  a1.x *= inv; a1.y *= inv; a1.z *= inv; a1.w *= inv;
  float4* __restrict__ O4 = (float4*)out;
  O4[(size_t)orow * D4C + lane * 2]     = a0;
  O4[(size_t)orow * D4C + lane * 2 + 1] = a1;
}

// ---- L2: mega pool (VALIDATED r9, verbatim — no prefetch, r13 lesson) ----
__global__ __launch_bounds__(256)
void mega_pool_kernel(const float* __restrict__ pieces,
                      const int* __restrict__ perm1, const int* __restrict__ offs1,
                      const int* __restrict__ perm2, const int* __restrict__ offs2,
                      const int* __restrict__ user_seg, int n_uni,
                      const float* __restrict__ itemj_piece,
                      const int* __restrict__ permj, const int* __restrict__ offsj,
                      const float* __restrict__ v0, const float* __restrict__ v1,
                      float* __restrict__ user_rep, float* __restrict__ itemi_out,
                      float* __restrict__ itemj_out, const int* __restrict__ pos_ptr) {
  const int bx = blockIdx.x;
  const int t = threadIdx.x;
  const int wid = t >> 6, lane = t & 63;
  const float4* __restrict__ V0 = (const float4*)v0;

  if (bx < BS_) {
    const float4* __restrict__ V1 = (const float4*)v1;
    const float4* __restrict__ X4 = (const float4*)pieces;
    float4 va0 = V0[lane * 2], vb0 = V0[lane * 2 + 1];
    float4 va1 = V1[lane * 2], vb1 = V1[lane * 2 + 1];
    int pos = *pos_ptr;
    pos = min(max(pos, 0), n_uni - BS_);
    const int u = bx;
    const int s2 = offs2[u], e2 = offs2[u + 1];

    float4 acc0 = make_float4(0.f, 0.f, 0.f, 0.f);
    float4 acc1 = make_float4(0.f, 0.f, 0.f, 0.f);
    float zz = 0.f;
    for (int k = s2 + wid; k < e2; k += 4) {
      const int rr = perm2[k];
      const int s1 = offs1[rr], e1 = offs1[rr + 1];
      float4 r0 = make_float4(0.f, 0.f, 0.f, 0.f);
      float4 r1 = make_float4(0.f, 0.f, 0.f, 0.f);
      float z1 = 0.f;
      for (int p = s1; p < e1; ++p) {
        int prow = perm1[p];
        float4 x0 = X4[(size_t)prow * D4C + lane * 2];
        float4 x1 = X4[(size_t)prow * D4C + lane * 2 + 1];
        float d = x0.x * va0.x + x0.y * va0.y + x0.z * va0.z + x0.w * va0.w
                + x1.x * vb0.x + x1.y * vb0.y + x1.z * vb0.z + x1.w * vb0.w;
        d = wave_reduce_sum(d);
        float w = expf(d);
        z1 += w;
        r0.x += w * x0.x; r0.y += w * x0.y; r0.z += w * x0.z; r0.w += w * x0.w;
        r1.x += w * x1.x; r1.y += w * x1.y; r1.z += w * x1.z; r1.w += w * x1.w;
      }
      float inv1 = (z1 > 0.f) ? 1.0f / z1 : 0.f;
      r0.x *= inv1; r0.y *= inv1; r0.z *= inv1; r0.w *= inv1;
      r1.x *= inv1; r1.y *= inv1; r1.z *= inv1; r1.w *= inv1;
      if (rr >= pos && rr < pos + BS_) {
        float4* __restrict__ O2 = (float4*)itemi_out;
        O2[(size_t)(rr - pos) * D4C + lane * 2]     = r0;
        O2[(size_t)(rr - pos) * D4C + lane * 2 + 1] = r1;
      }
      float d1 = r0.x * va1.x + r0.y * va1.y + r0.z * va1.z + r0.w * va1.w
               + r1.x * vb1.x + r1.y * vb1.y + r1.z * vb1.z + r1.w * vb1.w;
      d1 = wave_reduce_sum(d1);
      float e2w = expf(d1);
      zz += e2w;
      acc0.x += e2w * r0.x; acc0.y += e2w * r0.y;
      acc0.z += e2w * r0.z; acc0.w += e2w * r0.w;
      acc1.x += e2w * r1.x; acc1.y += e2w * r1.y;
      acc1.z += e2w * r1.z; acc1.w += e2w * r1.w;
    }
    __shared__ float4 pbuf[4][130];
    __shared__ float zbuf[4];
    pbuf[wid][lane * 2]     = acc0;
    pbuf[wid][lane * 2 + 1] = acc1;
    if (lane == 0) zbuf[wid] = zz;
    __syncthreads();
    if (wid == 0) {
      float4 A0 = make_float4(0.f, 0.f, 0.f, 0.f);
      float4 A1 = make_float4(0.f, 0.f, 0.f, 0.f);
      float Z = zbuf[0] + zbuf[1] + zbuf[2] + zbuf[3];
#pragma unroll
      for (int w = 0; w < 4; ++w) {
        float4 p0 = pbuf[w][lane * 2], p1 = pbuf[w][lane * 2 + 1];
        A0.x += p0.x; A0.y += p0.y; A0.z += p0.z; A0.w += p0.w;
        A1.x += p1.x; A1.y += p1.y; A1.z += p1.z; A1.w += p1.w;
      }
      float inv = (Z > 0.f) ? 1.0f / Z : 0.f;
      A0.x *= inv; A0.y *= inv; A0.z *= inv; A0.w *= inv;
      A1.x *= inv; A1.y *= inv; A1.z *= inv; A1.w *= inv;
      float4* __restrict__ O4 = (float4*)user_rep;
      O4[(size_t)u * D4C + lane * 2]     = A0;
      O4[(size_t)u * D4C + lane * 2 + 1] = A1;
    }
    return;
  }

  const int gridB = (BS_ + 3) >> 2;
  float4 va = V0[lane * 2], vb = V0[lane * 2 + 1];
  if (bx < BS_ + gridB) {
    int g = (bx - BS_) * 4 + wid;
    if (g >= BS_) return;
    pool_one(itemj_piece, permj, offsj, g, lane, va, vb, itemj_out, g);
  } else {
    int idx = (bx - BS_ - gridB) * 4 + wid;
    if (idx >= BS_) return;
    int pos = *pos_ptr;
    pos = min(max(pos, 0), n_uni - BS_);
    int rr = pos + idx;
    if ((unsigned)user_seg[rr] < (unsigned)BS_) return;
    pool_one(pieces, perm1, offs1, rr, lane, va, vb, itemi_out, idx);
  }
}

// ---- L3: fused latents + BPR scores (VALIDATED r8-r13, verbatim) ----
__global__ __launch_bounds__(1024)
void latpred_kernel(const float* __restrict__ user_rep, const float* __restrict__ itemi,
                    const float* __restrict__ itemj,
                    const float* __restrict__ user_W, const float* __restrict__ user_b,
                    const float* __restrict__ item_W, const float* __restrict__ item_b,
                    float* __restrict__ pred_i, float* __restrict__ pred_j) {
  const int rows0 = blockIdx.x * 8;
  const int t = threadIdx.x;

  __shared__ float4 lAu[8][129], lAi[8][129], lAj[8][129];
  __shared__ float si[8][129], sj[8][129];
  {
    const int r = t >> 7, c = t & 127;
    lAu[r][c] = ((const float4*)user_rep)[(size_t)(rows0 + r) * D4C + c];
    lAi[r][c] = ((const float4*)itemi)[(size_t)(rows0 + r) * D4C + c];
    lAj[r][c] = ((const float4*)itemj)[(size_t)(rows0 + r) * D4C + c];
  }
  __syncthreads();

  const int row = t & 7;
  const int f   = t >> 3;
  const float4* __restrict__ Wu = (const float4*)user_W;
  const float4* __restrict__ Wi = (const float4*)item_W;
  float au = 0.f, ai = 0.f, aj = 0.f;
  for (int k4 = 0; k4 < D4C; ++k4) {
    float4 u = lAu[row][k4];
    float4 i4 = lAi[row][k4];
    float4 j4 = lAj[row][k4];
    float4 wu = Wu[(size_t)f * D4C + k4];
    float4 wi = Wi[(size_t)f * D4C + k4];
    au += u.x * wu.x + u.y * wu.y + u.z * wu.z + u.w * wu.w;
    ai += i4.x * wi.x + i4.y * wi.y + i4.z * wi.z + i4.w * wi.w;
    aj += j4.x * wi.x + j4.y * wi.y + j4.z * wi.z + j4.w * wi.w;
  }
  float lu = au + user_b[f];
  float li = ai + item_b[f];
  float lj = aj + item_b[f];
  si[row][f] = lu * li;
  sj[row][f] = lu * lj;
  __syncthreads();

  const int wid = t >> 6, lane = t & 63;
  if (wid < 8) {
    float v = si[wid][lane] + si[wid][lane + 64];
    v = wave_reduce_sum(v);
    if (lane == 0) pred_i[rows0 + wid] = v;
  } else {
    int r = wid - 8;
    float v = sj[r][lane] + sj[r][lane + 64];
    v = wave_reduce_sum(v);
    if (lane == 0) pred_j[rows0 + r] = v;
  }
}

extern "C" void kernel_launch(void* const* d_in, const int* in_sizes, int n_in,
                              void* d_out, int out_size, void* d_ws, size_t ws_size,
                              hipStream_t stream) {
  const float* user_pooled = (const float*)d_in[0];
  const float* itemj_piece = (const float*)d_in[1];
  const float* Ws1   = (const float*)d_in[2];
  const float* ws2   = (const float*)d_in[3];
  const float* Ws01  = (const float*)d_in[4];
  const float* ws02  = (const float*)d_in[5];
  const float* user_W = (const float*)d_in[6];
  const float* user_b = (const float*)d_in[7];
  const float* item_W = (const float*)d_in[8];
  const float* item_b = (const float*)d_in[9];
  const int* piece_seg = (const int*)d_in[10];
  const int* user_seg  = (const int*)d_in[11];
  const int* itemj_seg = (const int*)d_in[12];
  const int* pos_ptr   = (const int*)d_in[13];

  const int P_U  = in_sizes[10];
  const int NUNI = in_sizes[11];
  const int P_J  = in_sizes[12];

  float* ws = (float*)d_ws;
  float* v0 = ws;                                    // 512
  float* v1 = ws + 512;                              // 512
  float* user_rep = ws + 1024;                       // BS*512
  int* ib = (int*)(user_rep + (size_t)BS_ * D_MODEL);
  int* perm1 = ib;                 ib += P_U;
  int* perm2 = ib;                 ib += NUNI;
  int* permj = ib;                 ib += P_J;
  int* offs1 = ib;                 ib += NUNI + 1;
  int* offs2 = ib;                 ib += BS_ + 1;
  int* offsj = ib;                 ib += BS_ + 1;

  float* outf = (float*)d_out;
  float* itemi_out = outf;
  float* itemj_out = outf + (size_t)BS_ * D_MODEL;
  float* pred_i = outf + 2 * (size_t)BS_ * D_MODEL;
  float* pred_j = pred_i + BS_;

  // L1: ALL prep (3 value-windowed sorts + vvec) — one launch, no cross-block deps
  const int nw1 = (NUNI + WIN_ - 1) / WIN_;          // 6 for NUNI=24576
  prep_all_kernel<<<nw1 + 2 + 8, 1024, 0, stream>>>(
      piece_seg, P_U, NUNI, offs1, perm1,
      user_seg, NUNI, BS_, offs2, perm2,
      itemj_seg, P_J, BS_, offsj, permj,
      Ws01, ws02, Ws1, ws2, v0, v1, nw1);

  // L2: fused pools (user path + itemj + itemi-fix)
  const int gridB = (BS_ + 3) / 4, gridC = (BS_ + 3) / 4;
  mega_pool_kernel<<<BS_ + gridB + gridC, 256, 0, stream>>>(
      user_pooled, perm1, offs1, perm2, offs2, user_seg, NUNI,
      itemj_piece, permj, offsj, v0, v1,
      user_rep, itemi_out, itemj_out, pos_ptr);

  // L3: latents + scores
  latpred_kernel<<<BS_ / 8, 1024, 0, stream>>>(user_rep, itemi_out, itemj_out,
                                               user_W, user_b, item_W, item_b,
                                               pred_i, pred_j);
}

// Round 15
// 140.200 us; speedup vs baseline: 2.3494x; 1.2035x over previous
//
#include <hip/hip_runtime.h>

#define D_MODEL 512
#define D4C     128   // D_MODEL / 4
#define DA_C    256
#define FACTOR_ 128
#define BS_     4096
#define WIN_    4096   // value-window width for the block-local counting sort

__device__ __forceinline__ float wave_reduce_sum(float x) {
#pragma unroll
  for (int o = 32; o; o >>= 1) x += __shfl_xor(x, o, 64);
  return x;
}
__device__ __forceinline__ int wave_reduce_sum_i(int x) {
#pragma unroll
  for (int o = 32; o; o >>= 1) x += __shfl_xor(x, o, 64);
  return x;
}

// ---- L1: ALL prep in ONE launch, zero cross-block dependencies ----
// (r14 structure; count/fill passes now int4-vectorized + unrolled for ILP)
__global__ __launch_bounds__(1024)
void prep_all_kernel(const int* __restrict__ seg1, int n1, int k1,
                     int* __restrict__ offs1, int* __restrict__ perm1,
                     const int* __restrict__ seg2, int n2, int k2,
                     int* __restrict__ offs2, int* __restrict__ perm2,
                     const int* __restrict__ seg3, int n3, int k3,
                     int* __restrict__ offs3, int* __restrict__ perm3,
                     const float* __restrict__ Ws01, const float* __restrict__ ws02,
                     const float* __restrict__ Ws1,  const float* __restrict__ ws2,
                     float* __restrict__ v0, float* __restrict__ v1, int nw1) {
  __shared__ int hist[WIN_];     // 16 KB: counts, then cursors
  __shared__ int obase[WIN_];    // 16 KB: scanned global offsets per bin
  __shared__ int wpre[17];
  __shared__ int below_sh[16];
  __shared__ float vred[8][128]; // 4 KB

  const int bx = blockIdx.x, t = threadIdx.x;
  const int lane = t & 63, wid = t >> 6;
  const int nsort = nw1 + 2;

  if (bx < nsort) {
    const int* seg; int n, k, lo, hi;
    int *offs, *perm;
    if (bx < nw1)      { seg = seg1; n = n1; k = k1; offs = offs1; perm = perm1;
                         lo = bx * WIN_; hi = min(lo + WIN_, k); }
    else if (bx == nw1){ seg = seg2; n = n2; k = k2; offs = offs2; perm = perm2;
                         lo = 0; hi = k; }
    else               { seg = seg3; n = n3; k = k3; offs = offs3; perm = perm3;
                         lo = 0; hi = k; }
    const int wk = hi - lo;
    const int n4 = n >> 2;
    const int4* __restrict__ seg4 = (const int4*)seg;

    for (int i = t; i < wk; i += 1024) hist[i] = 0;
    __syncthreads();

    // pass 1: window histogram + below-count (int4 + unroll: 16 elems in flight)
    int below = 0;
#pragma unroll 4
    for (int i = t; i < n4; i += 1024) {
      int4 v = seg4[i];
      unsigned a = (unsigned)v.x, b = (unsigned)v.y,
               c = (unsigned)v.z, d = (unsigned)v.w;
      if (a < (unsigned)lo) below++;
      else { unsigned l = a - (unsigned)lo; if (l < (unsigned)wk) atomicAdd(&hist[l], 1); }
      if (b < (unsigned)lo) below++;
      else { unsigned l = b - (unsigned)lo; if (l < (unsigned)wk) atomicAdd(&hist[l], 1); }
      if (c < (unsigned)lo) below++;
      else { unsigned l = c - (unsigned)lo; if (l < (unsigned)wk) atomicAdd(&hist[l], 1); }
      if (d < (unsigned)lo) below++;
      else { unsigned l = d - (unsigned)lo; if (l < (unsigned)wk) atomicAdd(&hist[l], 1); }
    }
    for (int i = n4 * 4 + t; i < n; i += 1024) {  // tail (none for this data)
      unsigned uv = (unsigned)seg[i];
      if (uv < (unsigned)lo) below++;
      else { unsigned l = uv - (unsigned)lo;
             if (l < (unsigned)wk) atomicAdd(&hist[l], 1); }
    }
    below = wave_reduce_sum_i(below);
    if (lane == 0) below_sh[wid] = below;
    __syncthreads();
    int base = 0;
#pragma unroll
    for (int i = 0; i < 16; ++i) base += below_sh[i];

    // in-LDS exclusive scan of hist -> obase (+ base), publish global offs
    const int per = (wk + 1023) / 1024;
    const int slo = min(t * per, wk), shi = min(slo + per, wk);
    int s = 0;
    for (int i = slo; i < shi; ++i) s += hist[i];
    int x = s;
#pragma unroll
    for (int o = 1; o < 64; o <<= 1) {
      int y = __shfl_up(x, o, 64);
      if (lane >= o) x += y;
    }
    if (lane == 63) wpre[wid] = x;
    __syncthreads();
    if (t == 0) {
      int acc = 0;
#pragma unroll
      for (int i = 0; i < 16; ++i) { int tmp = wpre[i]; wpre[i] = acc; acc += tmp; }
      wpre[16] = acc;
    }
    __syncthreads();
    int acc = base + wpre[wid] + (x - s);
    for (int i = slo; i < shi; ++i) {
      obase[i] = acc;
      offs[lo + i] = acc;
      acc += hist[i];
    }
    if (hi == k && t == 0) offs[k] = base + wpre[16];
    __syncthreads();

    // re-zero hist as cursors, then fill this window's perm entries (int4)
    for (int i = t; i < wk; i += 1024) hist[i] = 0;
    __syncthreads();
#pragma unroll 4
    for (int i = t; i < n4; i += 1024) {
      int4 v = seg4[i];
      const int rbase = i * 4;
      {
        unsigned l = (unsigned)v.x - (unsigned)lo;
        if (l < (unsigned)wk) { int pos = atomicAdd(&hist[l], 1); perm[obase[l] + pos] = rbase; }
      }
      {
        unsigned l = (unsigned)v.y - (unsigned)lo;
        if (l < (unsigned)wk) { int pos = atomicAdd(&hist[l], 1); perm[obase[l] + pos] = rbase + 1; }
      }
      {
        unsigned l = (unsigned)v.z - (unsigned)lo;
        if (l < (unsigned)wk) { int pos = atomicAdd(&hist[l], 1); perm[obase[l] + pos] = rbase + 2; }
      }
      {
        unsigned l = (unsigned)v.w - (unsigned)lo;
        if (l < (unsigned)wk) { int pos = atomicAdd(&hist[l], 1); perm[obase[l] + pos] = rbase + 3; }
      }
    }
    for (int i = n4 * 4 + t; i < n; i += 1024) {  // tail
      unsigned l = (unsigned)seg[i] - (unsigned)lo;
      if ((unsigned)seg[i] >= (unsigned)lo && l < (unsigned)wk) {
        int pos = atomicAdd(&hist[l], 1);
        perm[obase[l] + pos] = i;
      }
    }
    return;
  }

  // ---- vvec: 8 blocks, each 128 cols of one matrix (validated r11-r14) ----
  const int vb = bx - nsort;            // 0..7
  const int m = vb >> 2;
  const int c0 = (vb & 3) * 128;
  const float* W  = m ? Ws1 : Ws01;
  const float* w2 = m ? ws2 : ws02;
  const int col = t & 127;
  const int g = t >> 7;                 // 0..7, 32 a-rows each
  float s = 0.f;
  for (int a = g * 32; a < g * 32 + 32; ++a)
    s += w2[a] * W[a * D_MODEL + c0 + col];
  vred[g][col] = s;
  __syncthreads();
  if (t < 128) {
    float acc = 0.f;
#pragma unroll
    for (int q = 0; q < 8; ++q) acc += vred[q][t];
    (m ? v1 : v0)[c0 + t] = acc;
  }
}

// Pool one segment (wave-per-segment gather; VALIDATED r7-r14).
__device__ __forceinline__ void pool_one(const float* __restrict__ X,
                                         const int* __restrict__ perm,
                                         const int* __restrict__ offs, int g, int lane,
                                         float4 va, float4 vb, float* __restrict__ out,
                                         int orow) {
  const float4* __restrict__ X4 = (const float4*)X;
  const int s = offs[g], e = offs[g + 1];
  float4 a0 = make_float4(0.f, 0.f, 0.f, 0.f);
  float4 a1 = make_float4(0.f, 0.f, 0.f, 0.f);
  float z = 0.f;
  for (int p = s; p < e; ++p) {
    int row = perm[p];
    float4 x0 = X4[(size_t)row * D4C + lane * 2];
    float4 x1 = X4[(size_t)row * D4C + lane * 2 + 1];
    float d = x0.x * va.x + x0.y * va.y + x0.z * va.z + x0.w * va.w
            + x1.x * vb.x + x1.y * vb.y + x1.z * vb.z + x1.w * vb.w;
    d = wave_reduce_sum(d);
    float w = expf(d);
    z += w;
    a0.x += w * x0.x; a0.y += w * x0.y; a0.z += w * x0.z; a0.w += w * x0.w;
    a1.x += w * x1.x; a1.y += w * x1.y; a1.z += w * x1.z; a1.w += w * x1.w;
  }
  float inv = (z > 0.f) ? 1.0f / z : 0.f;
  a0.x *= inv; a0.y *= inv; a0.z *= inv; a0.w *= inv;
  a1.x *= inv; a1.y *= inv; a1.z *= inv; a1.w *= inv;
  float4* __restrict__ O4 = (float4*)out;
  O4[(size_t)orow * D4C + lane * 2]     = a0;
  O4[(size_t)orow * D4C + lane * 2 + 1] = a1;
}

// ---- L2: mega pool (VALIDATED r9/r14, verbatim) ----
__global__ __launch_bounds__(256)
void mega_pool_kernel(const float* __restrict__ pieces,
                      const int* __restrict__ perm1, const int* __restrict__ offs1,
                      const int* __restrict__ perm2, const int* __restrict__ offs2,
                      const int* __restrict__ user_seg, int n_uni,
                      const float* __restrict__ itemj_piece,
                      const int* __restrict__ permj, const int* __restrict__ offsj,
                      const float* __restrict__ v0, const float* __restrict__ v1,
                      float* __restrict__ user_rep, float* __restrict__ itemi_out,
                      float* __restrict__ itemj_out, const int* __restrict__ pos_ptr) {
  const int bx = blockIdx.x;
  const int t = threadIdx.x;
  const int wid = t >> 6, lane = t & 63;
  const float4* __restrict__ V0 = (const float4*)v0;

  if (bx < BS_) {
    const float4* __restrict__ V1 = (const float4*)v1;
    const float4* __restrict__ X4 = (const float4*)pieces;
    float4 va0 = V0[lane * 2], vb0 = V0[lane * 2 + 1];
    float4 va1 = V1[lane * 2], vb1 = V1[lane * 2 + 1];
    int pos = *pos_ptr;
    pos = min(max(pos, 0), n_uni - BS_);
    const int u = bx;
    const int s2 = offs2[u], e2 = offs2[u + 1];

    float4 acc0 = make_float4(0.f, 0.f, 0.f, 0.f);
    float4 acc1 = make_float4(0.f, 0.f, 0.f, 0.f);
    float zz = 0.f;
    for (int k = s2 + wid; k < e2; k += 4) {
      const int rr = perm2[k];
      const int s1 = offs1[rr], e1 = offs1[rr + 1];
      float4 r0 = make_float4(0.f, 0.f, 0.f, 0.f);
      float4 r1 = make_float4(0.f, 0.f, 0.f, 0.f);
      float z1 = 0.f;
      for (int p = s1; p < e1; ++p) {
        int prow = perm1[p];
        float4 x0 = X4[(size_t)prow * D4C + lane * 2];
        float4 x1 = X4[(size_t)prow * D4C + lane * 2 + 1];
        float d = x0.x * va0.x + x0.y * va0.y + x0.z * va0.z + x0.w * va0.w
                + x1.x * vb0.x + x1.y * vb0.y + x1.z * vb0.z + x1.w * vb0.w;
        d = wave_reduce_sum(d);
        float w = expf(d);
        z1 += w;
        r0.x += w * x0.x; r0.y += w * x0.y; r0.z += w * x0.z; r0.w += w * x0.w;
        r1.x += w * x1.x; r1.y += w * x1.y; r1.z += w * x1.z; r1.w += w * x1.w;
      }
      float inv1 = (z1 > 0.f) ? 1.0f / z1 : 0.f;
      r0.x *= inv1; r0.y *= inv1; r0.z *= inv1; r0.w *= inv1;
      r1.x *= inv1; r1.y *= inv1; r1.z *= inv1; r1.w *= inv1;
      if (rr >= pos && rr < pos + BS_) {
        float4* __restrict__ O2 = (float4*)itemi_out;
        O2[(size_t)(rr - pos) * D4C + lane * 2]     = r0;
        O2[(size_t)(rr - pos) * D4C + lane * 2 + 1] = r1;
      }
      float d1 = r0.x * va1.x + r0.y * va1.y + r0.z * va1.z + r0.w * va1.w
               + r1.x * vb1.x + r1.y * vb1.y + r1.z * vb1.z + r1.w * vb1.w;
      d1 = wave_reduce_sum(d1);
      float e2w = expf(d1);
      zz += e2w;
      acc0.x += e2w * r0.x; acc0.y += e2w * r0.y;
      acc0.z += e2w * r0.z; acc0.w += e2w * r0.w;
      acc1.x += e2w * r1.x; acc1.y += e2w * r1.y;
      acc1.z += e2w * r1.z; acc1.w += e2w * r1.w;
    }
    __shared__ float4 pbuf[4][130];
    __shared__ float zbuf[4];
    pbuf[wid][lane * 2]     = acc0;
    pbuf[wid][lane * 2 + 1] = acc1;
    if (lane == 0) zbuf[wid] = zz;
    __syncthreads();
    if (wid == 0) {
      float4 A0 = make_float4(0.f, 0.f, 0.f, 0.f);
      float4 A1 = make_float4(0.f, 0.f, 0.f, 0.f);
      float Z = zbuf[0] + zbuf[1] + zbuf[2] + zbuf[3];
#pragma unroll
      for (int w = 0; w < 4; ++w) {
        float4 p0 = pbuf[w][lane * 2], p1 = pbuf[w][lane * 2 + 1];
        A0.x += p0.x; A0.y += p0.y; A0.z += p0.z; A0.w += p0.w;
        A1.x += p1.x; A1.y += p1.y; A1.z += p1.z; A1.w += p1.w;
      }
      float inv = (Z > 0.f) ? 1.0f / Z : 0.f;
      A0.x *= inv; A0.y *= inv; A0.z *= inv; A0.w *= inv;
      A1.x *= inv; A1.y *= inv; A1.z *= inv; A1.w *= inv;
      float4* __restrict__ O4 = (float4*)user_rep;
      O4[(size_t)u * D4C + lane * 2]     = A0;
      O4[(size_t)u * D4C + lane * 2 + 1] = A1;
    }
    return;
  }

  const int gridB = (BS_ + 3) >> 2;
  float4 va = V0[lane * 2], vb = V0[lane * 2 + 1];
  if (bx < BS_ + gridB) {
    int g = (bx - BS_) * 4 + wid;
    if (g >= BS_) return;
    pool_one(itemj_piece, permj, offsj, g, lane, va, vb, itemj_out, g);
  } else {
    int idx = (bx - BS_ - gridB) * 4 + wid;
    if (idx >= BS_) return;
    int pos = *pos_ptr;
    pos = min(max(pos, 0), n_uni - BS_);
    int rr = pos + idx;
    if ((unsigned)user_seg[rr] < (unsigned)BS_) return;
    pool_one(pieces, perm1, offs1, rr, lane, va, vb, itemi_out, idx);
  }
}

// ---- L3: fused latents + BPR scores (VALIDATED r8-r14, verbatim) ----
__global__ __launch_bounds__(1024)
void latpred_kernel(const float* __restrict__ user_rep, const float* __restrict__ itemi,
                    const float* __restrict__ itemj,
                    const float* __restrict__ user_W, const float* __restrict__ user_b,
                    const float* __restrict__ item_W, const float* __restrict__ item_b,
                    float* __restrict__ pred_i, float* __restrict__ pred_j) {
  const int rows0 = blockIdx.x * 8;
  const int t = threadIdx.x;

  __shared__ float4 lAu[8][129], lAi[8][129], lAj[8][129];
  __shared__ float si[8][129], sj[8][129];
  {
    const int r = t >> 7, c = t & 127;
    lAu[r][c] = ((const float4*)user_rep)[(size_t)(rows0 + r) * D4C + c];
    lAi[r][c] = ((const float4*)itemi)[(size_t)(rows0 + r) * D4C + c];
    lAj[r][c] = ((const float4*)itemj)[(size_t)(rows0 + r) * D4C + c];
  }
  __syncthreads();

  const int row = t & 7;
  const int f   = t >> 3;
  const float4* __restrict__ Wu = (const float4*)user_W;
  const float4* __restrict__ Wi = (const float4*)item_W;
  float au = 0.f, ai = 0.f, aj = 0.f;
  for (int k4 = 0; k4 < D4C; ++k4) {
    float4 u = lAu[row][k4];
    float4 i4 = lAi[row][k4];
    float4 j4 = lAj[row][k4];
    float4 wu = Wu[(size_t)f * D4C + k4];
    float4 wi = Wi[(size_t)f * D4C + k4];
    au += u.x * wu.x + u.y * wu.y + u.z * wu.z + u.w * wu.w;
    ai += i4.x * wi.x + i4.y * wi.y + i4.z * wi.z + i4.w * wi.w;
    aj += j4.x * wi.x + j4.y * wi.y + j4.z * wi.z + j4.w * wi.w;
  }
  float lu = au + user_b[f];
  float li = ai + item_b[f];
  float lj = aj + item_b[f];
  si[row][f] = lu * li;
  sj[row][f] = lu * lj;
  __syncthreads();

  const int wid = t >> 6, lane = t & 63;
  if (wid < 8) {
    float v = si[wid][lane] + si[wid][lane + 64];
    v = wave_reduce_sum(v);
    if (lane == 0) pred_i[rows0 + wid] = v;
  } else {
    int r = wid - 8;
    float v = sj[r][lane] + sj[r][lane + 64];
    v = wave_reduce_sum(v);
    if (lane == 0) pred_j[rows0 + r] = v;
  }
}

extern "C" void kernel_launch(void* const* d_in, const int* in_sizes, int n_in,
                              void* d_out, int out_size, void* d_ws, size_t ws_size,
                              hipStream_t stream) {
  const float* user_pooled = (const float*)d_in[0];
  const float* itemj_piece = (const float*)d_in[1];
  const float* Ws1   = (const float*)d_in[2];
  const float* ws2   = (const float*)d_in[3];
  const float* Ws01  = (const float*)d_in[4];
  const float* ws02  = (const float*)d_in[5];
  const float* user_W = (const float*)d_in[6];
  const float* user_b = (const float*)d_in[7];
  const float* item_W = (const float*)d_in[8];
  const float* item_b = (const float*)d_in[9];
  const int* piece_seg = (const int*)d_in[10];
  const int* user_seg  = (const int*)d_in[11];
  const int* itemj_seg = (const int*)d_in[12];
  const int* pos_ptr   = (const int*)d_in[13];

  const int P_U  = in_sizes[10];
  const int NUNI = in_sizes[11];
  const int P_J  = in_sizes[12];

  float* ws = (float*)d_ws;
  float* v0 = ws;                                    // 512
  float* v1 = ws + 512;                              // 512
  float* user_rep = ws + 1024;                       // BS*512
  int* ib = (int*)(user_rep + (size_t)BS_ * D_MODEL);
  int* perm1 = ib;                 ib += P_U;
  int* perm2 = ib;                 ib += NUNI;
  int* permj = ib;                 ib += P_J;
  int* offs1 = ib;                 ib += NUNI + 1;
  int* offs2 = ib;                 ib += BS_ + 1;
  int* offsj = ib;                 ib += BS_ + 1;

  float* outf = (float*)d_out;
  float* itemi_out = outf;
  float* itemj_out = outf + (size_t)BS_ * D_MODEL;
  float* pred_i = outf + 2 * (size_t)BS_ * D_MODEL;
  float* pred_j = pred_i + BS_;

  // L1: ALL prep (3 value-windowed sorts + vvec) — one launch, no cross-block deps
  const int nw1 = (NUNI + WIN_ - 1) / WIN_;          // 6 for NUNI=24576
  prep_all_kernel<<<nw1 + 2 + 8, 1024, 0, stream>>>(
      piece_seg, P_U, NUNI, offs1, perm1,
      user_seg, NUNI, BS_, offs2, perm2,
      itemj_seg, P_J, BS_, offsj, permj,
      Ws01, ws02, Ws1, ws2, v0, v1, nw1);

  // L2: fused pools (user path + itemj + itemi-fix)
  const int gridB = (BS_ + 3) / 4, gridC = (BS_ + 3) / 4;
  mega_pool_kernel<<<BS_ + gridB + gridC, 256, 0, stream>>>(
      user_pooled, perm1, offs1, perm2, offs2, user_seg, NUNI,
      itemj_piece, permj, offsj, v0, v1,
      user_rep, itemi_out, itemj_out, pos_ptr);

  // L3: latents + scores
  latpred_kernel<<<BS_ / 8, 1024, 0, stream>>>(user_rep, itemi_out, itemj_out,
                                               user_W, user_b, item_W, item_b,
                                               pred_i, pred_j);
}

// Round 16
// 90.927 us; speedup vs baseline: 3.6226x; 1.5419x over previous
//
#include <hip/hip_runtime.h>

#define D_MODEL 512
#define D4C     128
#define DA_C    256
#define FACTOR_ 128
#define BS_     4096
#define WIN_    4096

typedef __attribute__((ext_vector_type(8))) short short8;
typedef __attribute__((ext_vector_type(4))) float f32x4;

__device__ __forceinline__ float wave_reduce_sum(float x) {
#pragma unroll
  for (int o = 32; o; o >>= 1) x += __shfl_xor(x, o, 64);
  return x;
}
__device__ __forceinline__ int wave_reduce_sum_i(int x) {
#pragma unroll
  for (int o = 32; o; o >>= 1) x += __shfl_xor(x, o, 64);
  return x;
}
__device__ __forceinline__ unsigned short f2bf(float f) {
  unsigned u = __float_as_uint(f);
  unsigned r = (u + 0x7FFF + ((u >> 16) & 1)) >> 16;   // RNE
  return (unsigned short)r;
}

// ---- L1: prep (3 windowed sorts + vvec + W bf16 casts), ONE launch ----
__global__ __launch_bounds__(1024)
void prep_all_kernel(const int* __restrict__ seg1, int n1, int k1,
                     int* __restrict__ offs1, int* __restrict__ perm1,
                     const int* __restrict__ seg2, int n2, int k2,
                     int* __restrict__ offs2, int* __restrict__ perm2,
                     const int* __restrict__ seg3, int n3, int k3,
                     int* __restrict__ offs3, int* __restrict__ perm3,
                     const float* __restrict__ Ws01, const float* __restrict__ ws02,
                     const float* __restrict__ Ws1,  const float* __restrict__ ws2,
                     float* __restrict__ v0, float* __restrict__ v1,
                     const float* __restrict__ user_W, const float* __restrict__ item_W,
                     unsigned short* __restrict__ uW_h, unsigned short* __restrict__ iW_h,
                     int nw1) {
  __shared__ int hist[WIN_];
  __shared__ int obase[WIN_];
  __shared__ int wpre[17];
  __shared__ int below_sh[16];
  __shared__ float vred[8][128];

  const int bx = blockIdx.x, t = threadIdx.x;
  const int lane = t & 63, wid = t >> 6;
  const int nsort = nw1 + 2;

  if (bx < nsort) {
    const int* seg; int n, k, lo, hi;
    int *offs, *perm;
    if (bx < nw1)      { seg = seg1; n = n1; k = k1; offs = offs1; perm = perm1;
                         lo = bx * WIN_; hi = min(lo + WIN_, k); }
    else if (bx == nw1){ seg = seg2; n = n2; k = k2; offs = offs2; perm = perm2;
                         lo = 0; hi = k; }
    else               { seg = seg3; n = n3; k = k3; offs = offs3; perm = perm3;
                         lo = 0; hi = k; }
    const int wk = hi - lo;
    const int n4 = n >> 2;
    const int4* __restrict__ seg4 = (const int4*)seg;

    for (int i = t; i < wk; i += 1024) hist[i] = 0;
    __syncthreads();

    int below = 0;
#pragma unroll 4
    for (int i = t; i < n4; i += 1024) {
      int4 v = seg4[i];
      unsigned a = (unsigned)v.x, b = (unsigned)v.y,
               c = (unsigned)v.z, d = (unsigned)v.w;
      if (a < (unsigned)lo) below++;
      else { unsigned l = a - (unsigned)lo; if (l < (unsigned)wk) atomicAdd(&hist[l], 1); }
      if (b < (unsigned)lo) below++;
      else { unsigned l = b - (unsigned)lo; if (l < (unsigned)wk) atomicAdd(&hist[l], 1); }
      if (c < (unsigned)lo) below++;
      else { unsigned l = c - (unsigned)lo; if (l < (unsigned)wk) atomicAdd(&hist[l], 1); }
      if (d < (unsigned)lo) below++;
      else { unsigned l = d - (unsigned)lo; if (l < (unsigned)wk) atomicAdd(&hist[l], 1); }
    }
    for (int i = n4 * 4 + t; i < n; i += 1024) {
      unsigned uv = (unsigned)seg[i];
      if (uv < (unsigned)lo) below++;
      else { unsigned l = uv - (unsigned)lo;
             if (l < (unsigned)wk) atomicAdd(&hist[l], 1); }
    }
    below = wave_reduce_sum_i(below);
    if (lane == 0) below_sh[wid] = below;
    __syncthreads();
    int base = 0;
#pragma unroll
    for (int i = 0; i < 16; ++i) base += below_sh[i];

    const int per = (wk + 1023) / 1024;
    const int slo = min(t * per, wk), shi = min(slo + per, wk);
    int s = 0;
    for (int i = slo; i < shi; ++i) s += hist[i];
    int x = s;
#pragma unroll
    for (int o = 1; o < 64; o <<= 1) {
      int y = __shfl_up(x, o, 64);
      if (lane >= o) x += y;
    }
    if (lane == 63) wpre[wid] = x;
    __syncthreads();
    if (t == 0) {
      int acc = 0;
#pragma unroll
      for (int i = 0; i < 16; ++i) { int tmp = wpre[i]; wpre[i] = acc; acc += tmp; }
      wpre[16] = acc;
    }
    __syncthreads();
    int acc = base + wpre[wid] + (x - s);
    for (int i = slo; i < shi; ++i) {
      obase[i] = acc;
      offs[lo + i] = acc;
      acc += hist[i];
    }
    if (hi == k && t == 0) offs[k] = base + wpre[16];
    __syncthreads();

    for (int i = t; i < wk; i += 1024) hist[i] = 0;
    __syncthreads();
#pragma unroll 4
    for (int i = t; i < n4; i += 1024) {
      int4 v = seg4[i];
      const int rbase = i * 4;
      { unsigned l = (unsigned)v.x - (unsigned)lo;
        if (l < (unsigned)wk) { int pos = atomicAdd(&hist[l], 1); perm[obase[l] + pos] = rbase; } }
      { unsigned l = (unsigned)v.y - (unsigned)lo;
        if (l < (unsigned)wk) { int pos = atomicAdd(&hist[l], 1); perm[obase[l] + pos] = rbase + 1; } }
      { unsigned l = (unsigned)v.z - (unsigned)lo;
        if (l < (unsigned)wk) { int pos = atomicAdd(&hist[l], 1); perm[obase[l] + pos] = rbase + 2; } }
      { unsigned l = (unsigned)v.w - (unsigned)lo;
        if (l < (unsigned)wk) { int pos = atomicAdd(&hist[l], 1); perm[obase[l] + pos] = rbase + 3; } }
    }
    for (int i = n4 * 4 + t; i < n; i += 1024) {
      unsigned l = (unsigned)seg[i] - (unsigned)lo;
      if ((unsigned)seg[i] >= (unsigned)lo && l < (unsigned)wk) {
        int pos = atomicAdd(&hist[l], 1);
        perm[obase[l] + pos] = i;
      }
    }
    return;
  }

  if (bx < nsort + 8) {
    // ---- vvec (validated r11-r15) ----
    const int vb = bx - nsort;
    const int m = vb >> 2;
    const int c0 = (vb & 3) * 128;
    const float* W  = m ? Ws1 : Ws01;
    const float* w2 = m ? ws2 : ws02;
    const int col = t & 127;
    const int g = t >> 7;
    float s = 0.f;
    for (int a = g * 32; a < g * 32 + 32; ++a)
      s += w2[a] * W[a * D_MODEL + c0 + col];
    vred[g][col] = s;
    __syncthreads();
    if (t < 128) {
      float acc = 0.f;
#pragma unroll
      for (int q = 0; q < 8; ++q) acc += vred[q][t];
      (m ? v1 : v0)[c0 + t] = acc;
    }
    return;
  }

  // ---- W -> bf16 cast (2 blocks) ----
  {
    const int w = bx - (nsort + 8);     // 0: user_W, 1: item_W
    const float4* __restrict__ src = (const float4*)(w ? item_W : user_W);
    ushort4* __restrict__ dst = (ushort4*)(w ? iW_h : uW_h);
    for (int i = t; i < FACTOR_ * D_MODEL / 4; i += 1024) {
      float4 v = src[i];
      ushort4 h;
      h.x = f2bf(v.x); h.y = f2bf(v.y); h.z = f2bf(v.z); h.w = f2bf(v.w);
      dst[i] = h;
    }
  }
}

// Pool one segment (wave gather; VALIDATED r7-r15) + optional bf16 copy.
__device__ __forceinline__ void pool_one(const float* __restrict__ X,
                                         const int* __restrict__ perm,
                                         const int* __restrict__ offs, int g, int lane,
                                         float4 va, float4 vb, float* __restrict__ out,
                                         int orow, unsigned short* __restrict__ hout) {
  const float4* __restrict__ X4 = (const float4*)X;
  const int s = offs[g], e = offs[g + 1];
  float4 a0 = make_float4(0.f, 0.f, 0.f, 0.f);
  float4 a1 = make_float4(0.f, 0.f, 0.f, 0.f);
  float z = 0.f;
  for (int p = s; p < e; ++p) {
    int row = perm[p];
    float4 x0 = X4[(size_t)row * D4C + lane * 2];
    float4 x1 = X4[(size_t)row * D4C + lane * 2 + 1];
    float d = x0.x * va.x + x0.y * va.y + x0.z * va.z + x0.w * va.w
            + x1.x * vb.x + x1.y * vb.y + x1.z * vb.z + x1.w * vb.w;
    d = wave_reduce_sum(d);
    float w = expf(d);
    z += w;
    a0.x += w * x0.x; a0.y += w * x0.y; a0.z += w * x0.z; a0.w += w * x0.w;
    a1.x += w * x1.x; a1.y += w * x1.y; a1.z += w * x1.z; a1.w += w * x1.w;
  }
  float inv = (z > 0.f) ? 1.0f / z : 0.f;
  a0.x *= inv; a0.y *= inv; a0.z *= inv; a0.w *= inv;
  a1.x *= inv; a1.y *= inv; a1.z *= inv; a1.w *= inv;
  float4* __restrict__ O4 = (float4*)out;
  O4[(size_t)orow * D4C + lane * 2]     = a0;
  O4[(size_t)orow * D4C + lane * 2 + 1] = a1;
  if (hout) {
    ushort4 h0, h1;
    h0.x = f2bf(a0.x); h0.y = f2bf(a0.y); h0.z = f2bf(a0.z); h0.w = f2bf(a0.w);
    h1.x = f2bf(a1.x); h1.y = f2bf(a1.y); h1.z = f2bf(a1.z); h1.w = f2bf(a1.w);
    ((ushort4*)hout)[(size_t)orow * D4C + lane * 2]     = h0;
    ((ushort4*)hout)[(size_t)orow * D4C + lane * 2 + 1] = h1;
  }
}

// ---- L2: mega pool (r9/r15 structure + bf16 rep emission) ----
__global__ __launch_bounds__(256)
void mega_pool_kernel(const float* __restrict__ pieces,
                      const int* __restrict__ perm1, const int* __restrict__ offs1,
                      const int* __restrict__ perm2, const int* __restrict__ offs2,
                      const int* __restrict__ user_seg, int n_uni,
                      const float* __restrict__ itemj_piece,
                      const int* __restrict__ permj, const int* __restrict__ offsj,
                      const float* __restrict__ v0, const float* __restrict__ v1,
                      unsigned short* __restrict__ urep_h,
                      unsigned short* __restrict__ itemi_h,
                      unsigned short* __restrict__ itemj_h,
                      float* __restrict__ itemi_out, float* __restrict__ itemj_out,
                      const int* __restrict__ pos_ptr) {
  const int bx = blockIdx.x;
  const int t = threadIdx.x;
  const int wid = t >> 6, lane = t & 63;
  const float4* __restrict__ V0 = (const float4*)v0;

  if (bx < BS_) {
    const float4* __restrict__ V1 = (const float4*)v1;
    const float4* __restrict__ X4 = (const float4*)pieces;
    float4 va0 = V0[lane * 2], vb0 = V0[lane * 2 + 1];
    float4 va1 = V1[lane * 2], vb1 = V1[lane * 2 + 1];
    int pos = *pos_ptr;
    pos = min(max(pos, 0), n_uni - BS_);
    const int u = bx;
    const int s2 = offs2[u], e2 = offs2[u + 1];

    float4 acc0 = make_float4(0.f, 0.f, 0.f, 0.f);
    float4 acc1 = make_float4(0.f, 0.f, 0.f, 0.f);
    float zz = 0.f;
    for (int k = s2 + wid; k < e2; k += 4) {
      const int rr = perm2[k];
      const int s1 = offs1[rr], e1 = offs1[rr + 1];
      float4 r0 = make_float4(0.f, 0.f, 0.f, 0.f);
      float4 r1 = make_float4(0.f, 0.f, 0.f, 0.f);
      float z1 = 0.f;
      for (int p = s1; p < e1; ++p) {
        int prow = perm1[p];
        float4 x0 = X4[(size_t)prow * D4C + lane * 2];
        float4 x1 = X4[(size_t)prow * D4C + lane * 2 + 1];
        float d = x0.x * va0.x + x0.y * va0.y + x0.z * va0.z + x0.w * va0.w
                + x1.x * vb0.x + x1.y * vb0.y + x1.z * vb0.z + x1.w * vb0.w;
        d = wave_reduce_sum(d);
        float w = expf(d);
        z1 += w;
        r0.x += w * x0.x; r0.y += w * x0.y; r0.z += w * x0.z; r0.w += w * x0.w;
        r1.x += w * x1.x; r1.y += w * x1.y; r1.z += w * x1.z; r1.w += w * x1.w;
      }
      float inv1 = (z1 > 0.f) ? 1.0f / z1 : 0.f;
      r0.x *= inv1; r0.y *= inv1; r0.z *= inv1; r0.w *= inv1;
      r1.x *= inv1; r1.y *= inv1; r1.z *= inv1; r1.w *= inv1;
      if (rr >= pos && rr < pos + BS_) {
        float4* __restrict__ O2 = (float4*)itemi_out;
        O2[(size_t)(rr - pos) * D4C + lane * 2]     = r0;
        O2[(size_t)(rr - pos) * D4C + lane * 2 + 1] = r1;
        ushort4 h0, h1;
        h0.x = f2bf(r0.x); h0.y = f2bf(r0.y); h0.z = f2bf(r0.z); h0.w = f2bf(r0.w);
        h1.x = f2bf(r1.x); h1.y = f2bf(r1.y); h1.z = f2bf(r1.z); h1.w = f2bf(r1.w);
        ((ushort4*)itemi_h)[(size_t)(rr - pos) * D4C + lane * 2]     = h0;
        ((ushort4*)itemi_h)[(size_t)(rr - pos) * D4C + lane * 2 + 1] = h1;
      }
      float d1 = r0.x * va1.x + r0.y * va1.y + r0.z * va1.z + r0.w * va1.w
               + r1.x * vb1.x + r1.y * vb1.y + r1.z * vb1.z + r1.w * vb1.w;
      d1 = wave_reduce_sum(d1);
      float e2w = expf(d1);
      zz += e2w;
      acc0.x += e2w * r0.x; acc0.y += e2w * r0.y;
      acc0.z += e2w * r0.z; acc0.w += e2w * r0.w;
      acc1.x += e2w * r1.x; acc1.y += e2w * r1.y;
      acc1.z += e2w * r1.z; acc1.w += e2w * r1.w;
    }
    __shared__ float4 pbuf[4][130];
    __shared__ float zbuf[4];
    pbuf[wid][lane * 2]     = acc0;
    pbuf[wid][lane * 2 + 1] = acc1;
    if (lane == 0) zbuf[wid] = zz;
    __syncthreads();
    if (wid == 0) {
      float4 A0 = make_float4(0.f, 0.f, 0.f, 0.f);
      float4 A1 = make_float4(0.f, 0.f, 0.f, 0.f);
      float Z = zbuf[0] + zbuf[1] + zbuf[2] + zbuf[3];
#pragma unroll
      for (int w = 0; w < 4; ++w) {
        float4 p0 = pbuf[w][lane * 2], p1 = pbuf[w][lane * 2 + 1];
        A0.x += p0.x; A0.y += p0.y; A0.z += p0.z; A0.w += p0.w;
        A1.x += p1.x; A1.y += p1.y; A1.z += p1.z; A1.w += p1.w;
      }
      float inv = (Z > 0.f) ? 1.0f / Z : 0.f;
      A0.x *= inv; A0.y *= inv; A0.z *= inv; A0.w *= inv;
      A1.x *= inv; A1.y *= inv; A1.z *= inv; A1.w *= inv;
      ushort4 h0, h1;
      h0.x = f2bf(A0.x); h0.y = f2bf(A0.y); h0.z = f2bf(A0.z); h0.w = f2bf(A0.w);
      h1.x = f2bf(A1.x); h1.y = f2bf(A1.y); h1.z = f2bf(A1.z); h1.w = f2bf(A1.w);
      ((ushort4*)urep_h)[(size_t)u * D4C + lane * 2]     = h0;
      ((ushort4*)urep_h)[(size_t)u * D4C + lane * 2 + 1] = h1;
    }
    return;
  }

  const int gridB = (BS_ + 3) >> 2;
  float4 va = V0[lane * 2], vb = V0[lane * 2 + 1];
  if (bx < BS_ + gridB) {
    int g = (bx - BS_) * 4 + wid;
    if (g >= BS_) return;
    pool_one(itemj_piece, permj, offsj, g, lane, va, vb, itemj_out, g, itemj_h);
  } else {
    int idx = (bx - BS_ - gridB) * 4 + wid;
    if (idx >= BS_) return;
    int pos = *pos_ptr;
    pos = min(max(pos, 0), n_uni - BS_);
    int rr = pos + idx;
    if ((unsigned)user_seg[rr] < (unsigned)BS_) return;
    pool_one(pieces, perm1, offs1, rr, lane, va, vb, itemi_out, idx, itemi_h);
  }
}

// ---- L3: MFMA latents + BPR scores ----
// Per block: 16 rep rows, 3 matrices x 8 ftiles x 16 ksteps of 16x16x32 bf16.
// Frag layout (m89-verified family): A row=lane&15, k=(lane>>4)*8+j;
// B col=lane&15, same k; D col=lane&15, row=(lane>>4)*4+j.
__global__ __launch_bounds__(256)
void latpred_mfma_kernel(const unsigned short* __restrict__ urep_h,
                         const unsigned short* __restrict__ itemi_h,
                         const unsigned short* __restrict__ itemj_h,
                         const unsigned short* __restrict__ uW_h,
                         const unsigned short* __restrict__ iW_h,
                         const float* __restrict__ user_b,
                         const float* __restrict__ item_b,
                         float* __restrict__ pred_i, float* __restrict__ pred_j) {
  __shared__ float lats[3][16][132];
  const int rowbase = blockIdx.x * 16;
  const int t = threadIdx.x;
  const int wave = t >> 6, lane = t & 63;
  const int sel = lane & 15;          // A-row / B-col selector
  const int kgrp = lane >> 4;         // 0..3

#pragma unroll
  for (int jj = 0; jj < 6; ++jj) {
    const int job = wave * 6 + jj;    // 0..23 = 3 mats x 8 ftiles
    const int mat = job >> 3;
    const int ftile = job & 7;
    const unsigned short* A = mat == 0 ? urep_h : (mat == 1 ? itemi_h : itemj_h);
    const unsigned short* W = mat == 0 ? uW_h : iW_h;
    const float* b = mat == 0 ? user_b : item_b;
    const int f = ftile * 16 + sel;
    const short8* __restrict__ Arow = (const short8*)(A + (size_t)(rowbase + sel) * D_MODEL);
    const short8* __restrict__ Wrow = (const short8*)(W + (size_t)f * D_MODEL);
    f32x4 acc = {0.f, 0.f, 0.f, 0.f};
#pragma unroll
    for (int ks = 0; ks < 16; ++ks) {
      short8 af = Arow[ks * 4 + kgrp];
      short8 bf = Wrow[ks * 4 + kgrp];
      acc = __builtin_amdgcn_mfma_f32_16x16x32_bf16(af, bf, acc, 0, 0, 0);
    }
    const float bias = b[f];
    const int orow0 = kgrp * 4;
#pragma unroll
    for (int j = 0; j < 4; ++j)
      lats[mat][orow0 + j][ftile * 16 + sel] = acc[j] + bias;
  }
  __syncthreads();

  // pred: thread t -> row t>>4, f-chunk (t&15)*8..+8; reduce over 16 chunks.
  const int row = t >> 4, c = t & 15;
  float pi = 0.f, pj = 0.f;
#pragma unroll
  for (int q = 0; q < 8; ++q) {
    const int f = c * 8 + q;
    const float lu = lats[0][row][f];
    pi += lu * lats[1][row][f];
    pj += lu * lats[2][row][f];
  }
#pragma unroll
  for (int o = 1; o < 16; o <<= 1) {
    pi += __shfl_xor(pi, o, 64);
    pj += __shfl_xor(pj, o, 64);
  }
  if (c == 0) {
    pred_i[rowbase + row] = pi;
    pred_j[rowbase + row] = pj;
  }
}

extern "C" void kernel_launch(void* const* d_in, const int* in_sizes, int n_in,
                              void* d_out, int out_size, void* d_ws, size_t ws_size,
                              hipStream_t stream) {
  const float* user_pooled = (const float*)d_in[0];
  const float* itemj_piece = (const float*)d_in[1];
  const float* Ws1   = (const float*)d_in[2];
  const float* ws2   = (const float*)d_in[3];
  const float* Ws01  = (const float*)d_in[4];
  const float* ws02  = (const float*)d_in[5];
  const float* user_W = (const float*)d_in[6];
  const float* user_b = (const float*)d_in[7];
  const float* item_W = (const float*)d_in[8];
  const float* item_b = (const float*)d_in[9];
  const int* piece_seg = (const int*)d_in[10];
  const int* user_seg  = (const int*)d_in[11];
  const int* itemj_seg = (const int*)d_in[12];
  const int* pos_ptr   = (const int*)d_in[13];

  const int P_U  = in_sizes[10];
  const int NUNI = in_sizes[11];
  const int P_J  = in_sizes[12];

  float* ws = (float*)d_ws;
  float* v0 = ws;                                    // 512
  float* v1 = ws + 512;                              // 512
  unsigned short* urep_h  = (unsigned short*)(ws + 1024);          // 4096*512
  unsigned short* itemi_h = urep_h + (size_t)BS_ * D_MODEL;
  unsigned short* itemj_h = itemi_h + (size_t)BS_ * D_MODEL;
  unsigned short* uW_h    = itemj_h + (size_t)BS_ * D_MODEL;       // 128*512
  unsigned short* iW_h    = uW_h + FACTOR_ * D_MODEL;
  int* ib = (int*)(iW_h + FACTOR_ * D_MODEL);
  int* perm1 = ib;                 ib += P_U;
  int* perm2 = ib;                 ib += NUNI;
  int* permj = ib;                 ib += P_J;
  int* offs1 = ib;                 ib += NUNI + 1;
  int* offs2 = ib;                 ib += BS_ + 1;
  int* offsj = ib;                 ib += BS_ + 1;

  float* outf = (float*)d_out;
  float* itemi_out = outf;
  float* itemj_out = outf + (size_t)BS_ * D_MODEL;
  float* pred_i = outf + 2 * (size_t)BS_ * D_MODEL;
  float* pred_j = pred_i + BS_;

  // L1: prep (sorts + vvec + W casts), one launch, no cross-block deps
  const int nw1 = (NUNI + WIN_ - 1) / WIN_;
  prep_all_kernel<<<nw1 + 2 + 8 + 2, 1024, 0, stream>>>(
      piece_seg, P_U, NUNI, offs1, perm1,
      user_seg, NUNI, BS_, offs2, perm2,
      itemj_seg, P_J, BS_, offsj, permj,
      Ws01, ws02, Ws1, ws2, v0, v1,
      user_W, item_W, uW_h, iW_h, nw1);

  // L2: fused pools (+ bf16 rep emission)
  const int gridB = (BS_ + 3) / 4, gridC = (BS_ + 3) / 4;
  mega_pool_kernel<<<BS_ + gridB + gridC, 256, 0, stream>>>(
      user_pooled, perm1, offs1, perm2, offs2, user_seg, NUNI,
      itemj_piece, permj, offsj, v0, v1,
      urep_h, itemi_h, itemj_h, itemi_out, itemj_out, pos_ptr);

  // L3: MFMA latents + scores
  latpred_mfma_kernel<<<BS_ / 16, 256, 0, stream>>>(
      urep_h, itemi_h, itemj_h, uW_h, iW_h, user_b, item_b, pred_i, pred_j);
}